// Round 16
// baseline (838.892 us; speedup 1.0000x reference)
//
#include <hip/hip_runtime.h>

#define N_NODES 50000
#define N_EDGES 250000
#define DIM 256          // IN = OUT = H*C
#define ED 194           // edge feature dim
#define EDP 256          // edge K padded to BK=64 multiple
#define MP_NODE 50048    // 391*128
#define MP_EDGE 250112   // 1954*128

typedef __bf16 bf16x8 __attribute__((ext_vector_type(8)));
typedef float f32x4 __attribute__((ext_vector_type(4)));
typedef short s16x8 __attribute__((ext_vector_type(8)));
typedef short s16x4 __attribute__((ext_vector_type(4)));
typedef unsigned short u16x8 __attribute__((ext_vector_type(8)));

__device__ __forceinline__ float bf2f(unsigned short b){
  union { unsigned int u; float f; } v; v.u = ((unsigned int)b)<<16; return v.f;
}
__device__ __forceinline__ short f2bf(float f){
  union { float f; unsigned int u; } v; v.f = f;
  unsigned int u = v.u;
  return (short)((u + 0x7fffu + ((u>>16)&1u))>>16);
}

// async global->LDS, 16B per lane. LDS dest = wave-uniform base + lane*16.
__device__ __forceinline__ void gload_lds16(const void* g, void* l){
  __builtin_amdgcn_global_load_lds(
      (const __attribute__((address_space(1))) unsigned int*)g,
      (__attribute__((address_space(3))) unsigned int*)l, 16, 0, 0);
}

// ---------------- input converts (fp32 -> bf16, padded) ----------------
__global__ __launch_bounds__(256) void convert_x_kernel(
    const float* __restrict__ x, short* __restrict__ xb, int* __restrict__ deg)
{
  int idx = blockIdx.x*256 + threadIdx.x;       // MP_NODE*64 float4s total
  if (idx < N_NODES) deg[idx] = 0;
  s16x4 o;
  if (idx < N_NODES*64){
    float4 a = *(const float4*)(x + (size_t)idx*4);
    o[0]=f2bf(a.x); o[1]=f2bf(a.y); o[2]=f2bf(a.z); o[3]=f2bf(a.w);
  } else {
    o[0]=0; o[1]=0; o[2]=0; o[3]=0;
  }
  *(s16x4*)(xb + (size_t)idx*4) = o;
}

// Edge rows are 194 floats (776B) -> stage 32 rows through LDS with dense
// flat float4 loads, then convert+pad (to EDP=256) with coalesced stores.
#define E_ROWS 32
__global__ __launch_bounds__(256) void convert_e_kernel(
    const float* __restrict__ ea, short* __restrict__ eb)
{
  __shared__ float lds[E_ROWS*ED];              // 6208 floats = 24832 B
  int row0 = blockIdx.x * E_ROWS;
  int tid = threadIdx.x;
  int base = row0 * ED;                         // float index of block start
  int valid = N_EDGES*ED - base;                // may be <=0 for pad blocks

  for (int i = tid; i < E_ROWS*ED/4; i += 256){
    float4 v;
    if (i*4 < valid) v = *(const float4*)(ea + base + i*4);
    else             v = make_float4(0.f,0.f,0.f,0.f);
    *(float4*)(lds + i*4) = v;
  }
  __syncthreads();

  for (int u = tid; u < E_ROWS*32; u += 256){
    int row = u >> 5;
    int c8  = u & 31;
    int col = c8*8;
    s16x8 o;
    if (col + 8 <= ED){
      #pragma unroll
      for (int j2=0;j2<4;j2++){
        float2 f = *(const float2*)(lds + row*ED + col + j2*2);
        o[j2*2]   = f2bf(f.x);
        o[j2*2+1] = f2bf(f.y);
      }
    } else {
      #pragma unroll
      for (int j=0;j<8;j++){
        int c = col + j;
        o[j] = (c < ED) ? f2bf(lds[row*ED + c]) : (short)0;
      }
    }
    *(s16x8*)(eb + (size_t)(row0+row)*EDP + col) = o;
  }
}

// ---------------- fused weight prep: BOTH convs, one launch (162 blocks) ----
__global__ __launch_bounds__(256) void prep_weights_all(
    const float* __restrict__ Wq1, const float* __restrict__ Wk1,
    const float* __restrict__ Wv1, const float* __restrict__ Ws1,
    const float* __restrict__ We1,
    const float* __restrict__ bq1, const float* __restrict__ bk1,
    const float* __restrict__ bv1, const float* __restrict__ bs1,
    const float* __restrict__ Wq2, const float* __restrict__ Wk2,
    const float* __restrict__ Wv2, const float* __restrict__ Ws2,
    const float* __restrict__ We2,
    const float* __restrict__ bq2, const float* __restrict__ bk2,
    const float* __restrict__ bv2, const float* __restrict__ bs2,
    short* __restrict__ WtN1, short* __restrict__ WtN2,
    short* __restrict__ WtE, float* __restrict__ biasN1, float* __restrict__ biasN2)
{
  __shared__ short lds[64*65];
  int b = blockIdx.x, tid = threadIdx.x;
  if (b < 128){
    int conv = b>>6, bb = b&63;
    int mat = bb>>4, tile = bb&15;
    int i0 = (tile>>2)*64, o0 = (tile&3)*64;
    const float* W = conv ? ((mat==0)?Wq2:((mat==1)?Wk2:((mat==2)?Wv2:Ws2)))
                          : ((mat==0)?Wq1:((mat==1)?Wk1:((mat==2)?Wv1:Ws1)));
    short* WtN = conv ? WtN2 : WtN1;
    #pragma unroll
    for (int t=0;t<16;t++){
      int idx = t*256+tid; int r = idx>>6, c = idx&63;
      lds[r*65+c] = f2bf(W[(size_t)(i0+r)*256 + o0 + c]);
    }
    __syncthreads();
    #pragma unroll
    for (int t=0;t<4;t++){
      int idx = t*256+tid; int r = idx>>4, c4 = (idx&15)*4;
      s16x4 o;
      o[0]=lds[(c4+0)*65+r]; o[1]=lds[(c4+1)*65+r];
      o[2]=lds[(c4+2)*65+r]; o[3]=lds[(c4+3)*65+r];
      *(s16x4*)(WtN + (mat<<16) + (o0+r)*256 + i0 + c4) = o;
    }
  } else if (b < 160){
    int b2 = b-128;                 // 32 blocks: 4 k-tiles x 8 o-tiles
    int k0 = (b2>>3)*64, o0 = (b2&7)*64;   // o0 in 0..511, k0 in 0..192
    const float* We = (o0 < 256) ? We1 : We2;
    int oc = o0 & 255;
    #pragma unroll
    for (int t=0;t<16;t++){
      int idx = t*256+tid; int r = idx>>6, c = idx&63;
      int k = k0+r;
      lds[r*65+c] = (k<ED) ? f2bf(We[(size_t)k*256 + oc + c]) : (short)0;
    }
    __syncthreads();
    #pragma unroll
    for (int t=0;t<4;t++){
      int idx = t*256+tid; int r = idx>>4, c4 = (idx&15)*4;
      if (k0 + c4 < EDP){
        s16x4 o;
        o[0]=lds[(c4+0)*65+r]; o[1]=lds[(c4+1)*65+r];
        o[2]=lds[(c4+2)*65+r]; o[3]=lds[(c4+3)*65+r];
        *(s16x4*)(WtE + (size_t)(o0+r)*EDP + k0 + c4) = o;
      }
    }
  } else {
    int conv = b - 160;
    float* biasN = conv ? biasN2 : biasN1;
    for (int t = tid; t < 1024; t += 256){
      const float* bb = conv ? ((t<256)?bq2:((t<512)?bk2:((t<768)?bv2:bs2)))
                             : ((t<256)?bq1:((t<512)?bk1:((t<768)?bv1:bs1)));
      biasN[t] = bb[t&255];
    }
  }
}

// ---------------- CSR build ----------------
__global__ __launch_bounds__(256) void count_deg(const int* __restrict__ dst, int* __restrict__ deg){
  int e = blockIdx.x*256 + threadIdx.x;
  if (e < N_EDGES) atomicAdd(&deg[dst[e]], 1);
}
#define SCAN_NBLK 196
__global__ __launch_bounds__(256) void scan_p1(const int* __restrict__ deg, int* __restrict__ part){
  int t = threadIdx.x;
  int i = blockIdx.x*256 + t;
  int v = (i<N_NODES)? deg[i] : 0;
  #pragma unroll
  for (int off=32; off; off>>=1) v += __shfl_xor(v, off, 64);
  __shared__ int s[4];
  if ((t&63)==0) s[t>>6] = v;
  __syncthreads();
  if (t==0) part[blockIdx.x] = s[0]+s[1]+s[2]+s[3];
}
__global__ __launch_bounds__(256) void scan_p2(int* __restrict__ part){
  __shared__ int s[256];
  int t = threadIdx.x;
  int v = (t<SCAN_NBLK)? part[t] : 0;
  s[t] = v; __syncthreads();
  for (int off=1; off<256; off<<=1){
    int x = (t>=off)? s[t-off] : 0;
    __syncthreads();
    s[t] += x;
    __syncthreads();
  }
  part[t] = (t==0)? 0 : s[t-1];
}
// also zeroes cursor
__global__ __launch_bounds__(256) void scan_p3(const int* __restrict__ deg,
    const int* __restrict__ part, int* __restrict__ rowptr, int* __restrict__ cursor){
  __shared__ int s[256];
  int t = threadIdx.x;
  int i = blockIdx.x*256 + t;
  int v = (i<N_NODES)? deg[i] : 0;
  s[t] = v; __syncthreads();
  for (int off=1; off<256; off<<=1){
    int x = (t>=off)? s[t-off] : 0;
    __syncthreads();
    s[t] += x;
    __syncthreads();
  }
  if (i < N_NODES){ rowptr[i+1] = part[blockIdx.x] + s[t]; cursor[i] = 0; }
  if (i == 0) rowptr[0] = 0;
}
// csr entries premultiplied to byte offsets:
//   x = src*2048 (QKVS row), y = e*1024 (Eemb row, 512 bf16 cols for both convs)
__global__ __launch_bounds__(256) void scatter_edges(
    const int* __restrict__ src, const int* __restrict__ dst,
    const int* __restrict__ rowptr, int* __restrict__ cursor, int2* __restrict__ csr)
{
  int e = blockIdx.x*256 + threadIdx.x;
  if (e < N_EDGES){
    int d = dst[e];
    int pos = atomicAdd(&cursor[d], 1);
    csr[rowptr[d] + pos] = make_int2(src[e]<<11, e<<10);
  }
}

// ---------------- GEMM body: out = A(bf16,[Mpad][256]) @ Bt^T ----------------
// r13/r15-proven structure (the 812.6us base): 128x128 tile, 4 waves, BK=64,
// single-buffered 32KB LDS (implicit wave-overlap hides latency), within-row
// XOR chunk swizzle (r13: conflicts 7M->0), same-XCD A-sharing block swizzle
// (r12: FETCH 245->57MB): bid -> xcd=bid&7, w=bid>>3, n=w%NB, m=(w/NB)*8+xcd
// (+ linear tail). K fixed at 256 (EDP padded); NLD/bias/NB runtime.
// (r14 dbuf+counted-vmcnt REGRESSED: 64KB LDS halved occupancy. r11 NT stores:
//  WRITE 2x. r10 n-fastest: cross-XCD. r4 128x256: occupancy. r5 frag-major:
//  broke VMEM coalescing.)
__device__ __forceinline__ void gemm_body(
    int bid, int MB, int NB,
    const short* __restrict__ A, const short* __restrict__ Bt,
    const float* __restrict__ bias, short* __restrict__ out, int M, int NLD,
    short* As, short* Bs)
{
  const int K = 256;
  int tid = threadIdx.x;
  int lane = tid & 63, wave = tid >> 6;

  int mblk, nblk;
  {
    int MB8 = MB & ~7;
    int body = MB8 * NB;
    if (bid < body){
      int xcd = bid & 7, w = bid >> 3;
      nblk = w % NB;
      mblk = (w / NB) * 8 + xcd;
    } else {
      int r = bid - body;
      mblk = MB8 + r / NB;
      nblk = r % NB;
    }
  }
  int m0 = mblk*128, n0 = nblk*128;

  // staging: wave w, lane l covers row w*8+(l>>3) (+ i*32 per instruction),
  // LDS chunk l&7; global source chunk (l&7)^((l>>3)&7)  [row&7 == (l>>3)&7]
  int srow = wave*8 + (lane>>3);
  int sx   = ((lane&7) ^ ((lane>>3)&7))*8;      // swizzled source col (shorts)
  const short* gA = A + (size_t)(m0+srow)*K + sx;
  const short* gB = Bt + (size_t)(n0+srow)*K + sx;
  short* ldsA = As + wave*512;                  // + i*2048 per instruction
  short* ldsB = Bs + wave*512;

  int wr = wave>>1, wc = wave&1;
  int fr = lane & 15;
  int kq = lane >> 4;
  int frx = fr & 7;
  const short* arb = As + (wr*64 + fr)*64;      // fragment row base (64-col rows)
  const short* brb = Bs + (wc*64 + fr)*64;

  f32x4 acc[4][4];
  #pragma unroll
  for (int a=0;a<4;a++)
    #pragma unroll
    for (int b=0;b<4;b++) acc[a][b] = (f32x4){0.f,0.f,0.f,0.f};

  for (int k0=0; k0<K; k0+=64){
    __syncthreads();
    #pragma unroll
    for (int i=0;i<4;i++){
      gload_lds16(gA + (size_t)i*32*K + k0, ldsA + i*2048);
      gload_lds16(gB + (size_t)i*32*K + k0, ldsB + i*2048);
    }
    __syncthreads();

    #pragma unroll
    for (int ks=0; ks<2; ks++){
      int cA = ((ks*4 + kq) ^ frx)*8;           // swizzled read chunk offset
      bf16x8 af[4], bf[4];
      #pragma unroll
      for (int fm=0;fm<4;fm++) af[fm] = *(const bf16x8*)(arb + fm*1024 + cA);
      #pragma unroll
      for (int fn=0;fn<4;fn++) bf[fn] = *(const bf16x8*)(brb + fn*1024 + cA);
      #pragma unroll
      for (int fm=0;fm<4;fm++)
        #pragma unroll
        for (int fn=0;fn<4;fn++)
          acc[fm][fn] = __builtin_amdgcn_mfma_f32_16x16x32_bf16(af[fm], bf[fn], acc[fm][fn], 0, 0, 0);
    }
  }

  int cr = (lane>>4)*4;
  int cc = lane & 15;
  #pragma unroll
  for (int fm=0;fm<4;fm++){
    #pragma unroll
    for (int fn=0;fn<4;fn++){
      int col = n0 + wc*64 + fn*16 + cc;
      float bv = bias ? bias[col] : 0.f;
      #pragma unroll
      for (int i=0;i<4;i++){
        int row = m0 + wr*64 + fm*16 + cr + i;
        if (row < M) out[(size_t)row*NLD + col] = f2bf(acc[fm][fn][i] + bv);
      }
    }
  }
}

#define EDGE_GBLK ((MP_EDGE/128)*4)   // 7816 (multiple of 8 -> XCD map stays aligned)

// edge GEMM + conv1 node GEMM fused: independent (e_bf/WtE vs x_bf/WtN1), so
// the node blocks backfill CUs as edge blocks retire — removes the serial
// boundary between the two biggest GEMMs.
__global__ __launch_bounds__(256) void gemm_fused1(
    const short* __restrict__ e_bf, const short* __restrict__ WtE,
    short* __restrict__ Eemb,
    const short* __restrict__ x_bf, const short* __restrict__ WtN1,
    const float* __restrict__ biasN1, short* __restrict__ QKVS)
{
  __shared__ short As[128*64];   // 16 KB
  __shared__ short Bs[128*64];   // 16 KB
  int bid = blockIdx.x;
  if (bid < EDGE_GBLK)
    gemm_body(bid, MP_EDGE/128, 4, e_bf, WtE, nullptr, Eemb, N_EDGES, 512, As, Bs);
  else
    gemm_body(bid-EDGE_GBLK, MP_NODE/128, 8, x_bf, WtN1, biasN1, QKVS, N_NODES, 1024, As, Bs);
}

__global__ __launch_bounds__(256) void gemm_single(
    const short* __restrict__ A, const short* __restrict__ Bt,
    const float* __restrict__ bias, short* __restrict__ out, int M, int NLD, int NB)
{
  __shared__ short As[128*64];
  __shared__ short Bs[128*64];
  gemm_body(blockIdx.x, gridDim.x/NB, NB, A, Bt, bias, out, M, NLD, As, Bs);
}

// ---------------- fused edge phase ----------------
// ONE WAVE PER NODE (4 nodes per block, no __syncthreads, no LDS merge).
// 32 lanes per edge, 8 channels per lane (16B loads), TWO edges in flight
// (half = lane>>5). csr entry for the NEXT iteration software-prefetched.
// Eemb rows are 512 bf16 (both convs); caller passes base +0 (conv1) or +256.
__global__ __launch_bounds__(256) void edge_phase_kernel(
    const short* __restrict__ QKVS, const short* __restrict__ Eemb,
    const int* __restrict__ rowptr, const int2* __restrict__ csr,
    short* __restrict__ out_bf, float* __restrict__ out_f, int relu)
{
  int tid = threadIdx.x, wave = tid>>6, lane = tid&63;
  int node = blockIdx.x*4 + wave;
  if (node >= N_NODES){
    if (node < MP_NODE && out_bf){
      s16x4 z; z[0]=0; z[1]=0; z[2]=0; z[3]=0;
      *(s16x4*)(out_bf + (size_t)node*256 + lane*4) = z;
    }
    return;
  }
  int half = lane>>5;          // which edge of the pair
  int hl   = lane&31;          // channel-group 0..31 (8 ch each)
  int c8   = hl*8;
  const unsigned short* base = (const unsigned short*)QKVS + (size_t)node*1024;

  u16x8 qu = *(const u16x8*)(base + c8);
  float q[8];
  #pragma unroll
  for (int j=0;j<8;j++) q[j] = bf2f(qu[j])*0.125f;

  int beg = rowptr[node], end = rowptr[node+1];
  float l = 0.f;
  float a[8];
  #pragma unroll
  for (int j=0;j<8;j++) a[j] = 0.f;
  int kb = 512 + hl*16;        // K byte offset within QKVS row for this lane
  int ebo = hl*16;             // Eemb byte offset within row-half

  if (beg < end){
    int j0 = beg + half;
    int2 se = csr[(j0 < end) ? j0 : (end-1)];
    for (int idx = beg; idx < end; idx += 2){
      int jn = idx + 2 + half;
      int2 se_n = csr[(jn < end) ? jn : (end-1)];   // prefetch next iteration
      int j = idx + half;
      const char* Kp = (const char*)QKVS + (unsigned)(se.x + kb);
      const char* Ep = (const char*)Eemb + (unsigned)(se.y + ebo);
      u16x8 ku = *(const u16x8*)Kp;
      u16x8 vu = *(const u16x8*)(Kp + 512);   // V block
      u16x8 eu = *(const u16x8*)Ep;
      float vv[8];
      float t = 0.f;
      #pragma unroll
      for (int c=0;c<8;c++){
        float ef = bf2f(eu[c]);
        float kf = bf2f(ku[c]) + ef;
        vv[c]    = bf2f(vu[c]) + ef;
        t += q[c]*kf;
      }
      t += __shfl_xor(t, 1, 64);
      t += __shfl_xor(t, 2, 64);
      t += __shfl_xor(t, 4, 64);
      float p = (j < end) ? __expf(t) : 0.f;
      l += p;
      #pragma unroll
      for (int c=0;c<8;c++) a[c] += p*vv[c];
      se = se_n;
    }
  }

  // merge the two halves (each summed a disjoint subset of edges)
  l += __shfl_xor(l, 32, 64);
  #pragma unroll
  for (int c=0;c<8;c++) a[c] += __shfl_xor(a[c], 32, 64);

  float inv = (l > 0.f) ? 1.0f/l : 0.f;
  u16x8 su = *(const u16x8*)(base + 768 + c8);   // skip = x@Ws + bs
  float r[8];
  #pragma unroll
  for (int c=0;c<8;c++){
    float v = a[c]*inv + bf2f(su[c]);
    r[c] = relu ? fmaxf(v, 0.f) : v;
  }

  if (out_bf){
    if (!half){
      s16x8 o;
      #pragma unroll
      for (int c=0;c<8;c++) o[c] = f2bf(r[c]);
      *(s16x8*)(out_bf + (size_t)node*256 + c8) = o;
    }
  } else {
    float4 st = half ? make_float4(r[4],r[5],r[6],r[7])
                     : make_float4(r[0],r[1],r[2],r[3]);
    *(float4*)(out_f + (size_t)node*256 + c8 + half*4) = st;
  }
}

// ---------------- launch ----------------
extern "C" void kernel_launch(void* const* d_in, const int* in_sizes, int n_in,
                              void* d_out, int out_size, void* d_ws, size_t ws_size,
                              hipStream_t stream)
{
  const float* x     = (const float*)d_in[0];
  const int*   eidx  = (const int*)d_in[1];
  const float* eattr = (const float*)d_in[2];
  const float* Wq1=(const float*)d_in[3],  *bq1=(const float*)d_in[4];
  const float* Wk1=(const float*)d_in[5],  *bk1=(const float*)d_in[6];
  const float* Wv1=(const float*)d_in[7],  *bv1=(const float*)d_in[8];
  const float* We1=(const float*)d_in[9];
  const float* Ws1=(const float*)d_in[10], *bs1=(const float*)d_in[11];
  const float* Wq2=(const float*)d_in[12], *bq2=(const float*)d_in[13];
  const float* Wk2=(const float*)d_in[14], *bk2=(const float*)d_in[15];
  const float* Wv2=(const float*)d_in[16], *bv2=(const float*)d_in[17];
  const float* We2=(const float*)d_in[18];
  const float* Ws2=(const float*)d_in[19], *bs2=(const float*)d_in[20];

  char* ws = (char*)d_ws;
  size_t off = 0;
  auto alloc = [&](size_t bytes)->char*{
    char* p = ws + off; off = (off + bytes + 255) & ~(size_t)255; return p;
  };
  short* QKVS  = (short*)alloc((size_t)N_NODES*1024*2);
  short* Eemb  = (short*)alloc((size_t)MP_EDGE*512*2);   // 512 cols: conv1|conv2
  short* x_bf  = (short*)alloc((size_t)MP_NODE*DIM*2);
  short* h_bf  = (short*)alloc((size_t)MP_NODE*DIM*2);
  short* e_bf  = (short*)alloc((size_t)MP_EDGE*EDP*2);   // K padded to 256
  short* WtN1  = (short*)alloc((size_t)4*65536*2);
  short* WtN2  = (short*)alloc((size_t)4*65536*2);
  short* WtE   = (short*)alloc((size_t)512*EDP*2);
  float* biasN1= (float*)alloc((size_t)1024*4);
  float* biasN2= (float*)alloc((size_t)1024*4);
  int*   deg   = (int*)alloc((size_t)N_NODES*4);
  int*   rowptr= (int*)alloc((size_t)(N_NODES+1)*4);
  int*   cursor= (int*)alloc((size_t)N_NODES*4);
  int*   part  = (int*)alloc((size_t)256*4);
  int2*  csr   = (int2*)alloc((size_t)N_EDGES*8);

  const int* srcp = eidx;
  const int* dstp = eidx + N_EDGES;

  const int EB = (N_EDGES + 255)/256;   // 977

  convert_x_kernel<<<MP_NODE*64/256,256,0,stream>>>(x, x_bf, deg);
  convert_e_kernel<<<MP_EDGE/E_ROWS,256,0,stream>>>(eattr, e_bf);

  count_deg<<<EB,256,0,stream>>>(dstp, deg);
  scan_p1<<<SCAN_NBLK,256,0,stream>>>(deg, part);
  scan_p2<<<1,256,0,stream>>>(part);
  scan_p3<<<SCAN_NBLK,256,0,stream>>>(deg, part, rowptr, cursor);
  scatter_edges<<<EB,256,0,stream>>>(srcp, dstp, rowptr, cursor, csr);

  prep_weights_all<<<162,256,0,stream>>>(
      Wq1,Wk1,Wv1,Ws1,We1,bq1,bk1,bv1,bs1,
      Wq2,Wk2,Wv2,Ws2,We2,bq2,bk2,bv2,bs2,
      WtN1,WtN2,WtE,biasN1,biasN2);

  // FUSED: merged edge GEMM (blocks [0,7816)) + conv1 node GEMM (rest).
  // Independent inputs -> node blocks backfill as edge blocks retire.
  gemm_fused1<<<EDGE_GBLK + (MP_NODE/128)*8,256,0,stream>>>(
      e_bf, WtE, Eemb, x_bf, WtN1, biasN1, QKVS);

  // ---- conv1 edge phase ----
  edge_phase_kernel<<<MP_NODE/4,256,0,stream>>>(QKVS,Eemb,rowptr,csr,h_bf,nullptr,1);

  // ---- conv2 ----
  gemm_single<<<(MP_NODE/128)*8,256,0,stream>>>(h_bf, WtN2, biasN2, QKVS, N_NODES, 1024, 8);
  edge_phase_kernel<<<N_NODES/4,256,0,stream>>>(QKVS,Eemb+256,rowptr,csr,nullptr,(float*)d_out,0);
}

// Round 17
// 808.669 us; speedup vs baseline: 1.0374x; 1.0374x over previous
//
#include <hip/hip_runtime.h>

#define N_NODES 50000
#define N_EDGES 250000
#define DIM 256          // IN = OUT = H*C
#define ED 194           // edge feature dim
#define EDP 256          // edge K padded to BK=64 multiple
#define MP_NODE 50048    // 391*128
#define MP_EDGE 250112   // 1954*128

typedef __bf16 bf16x8 __attribute__((ext_vector_type(8)));
typedef float f32x4 __attribute__((ext_vector_type(4)));
typedef short s16x8 __attribute__((ext_vector_type(8)));
typedef short s16x4 __attribute__((ext_vector_type(4)));
typedef unsigned short u16x8 __attribute__((ext_vector_type(8)));

__device__ __forceinline__ float bf2f(unsigned short b){
  union { unsigned int u; float f; } v; v.u = ((unsigned int)b)<<16; return v.f;
}
__device__ __forceinline__ short f2bf(float f){
  union { float f; unsigned int u; } v; v.f = f;
  unsigned int u = v.u;
  return (short)((u + 0x7fffu + ((u>>16)&1u))>>16);
}

// async global->LDS, 16B per lane. LDS dest = wave-uniform base + lane*16.
__device__ __forceinline__ void gload_lds16(const void* g, void* l){
  __builtin_amdgcn_global_load_lds(
      (const __attribute__((address_space(1))) unsigned int*)g,
      (__attribute__((address_space(3))) unsigned int*)l, 16, 0, 0);
}

// ---------------- input converts (fp32 -> bf16, padded) ----------------
__global__ __launch_bounds__(256) void convert_x_kernel(
    const float* __restrict__ x, short* __restrict__ xb, int* __restrict__ deg)
{
  int idx = blockIdx.x*256 + threadIdx.x;       // MP_NODE*64 float4s total
  if (idx < N_NODES) deg[idx] = 0;
  s16x4 o;
  if (idx < N_NODES*64){
    float4 a = *(const float4*)(x + (size_t)idx*4);
    o[0]=f2bf(a.x); o[1]=f2bf(a.y); o[2]=f2bf(a.z); o[3]=f2bf(a.w);
  } else {
    o[0]=0; o[1]=0; o[2]=0; o[3]=0;
  }
  *(s16x4*)(xb + (size_t)idx*4) = o;
}

// Edge rows are 194 floats (776B) -> stage 32 rows through LDS with dense
// flat float4 loads, then convert+pad (to EDP=256) with coalesced stores.
#define E_ROWS 32
__global__ __launch_bounds__(256) void convert_e_kernel(
    const float* __restrict__ ea, short* __restrict__ eb)
{
  __shared__ float lds[E_ROWS*ED];              // 6208 floats = 24832 B
  int row0 = blockIdx.x * E_ROWS;
  int tid = threadIdx.x;
  int base = row0 * ED;                         // float index of block start
  int valid = N_EDGES*ED - base;                // may be <=0 for pad blocks

  for (int i = tid; i < E_ROWS*ED/4; i += 256){
    float4 v;
    if (i*4 < valid) v = *(const float4*)(ea + base + i*4);
    else             v = make_float4(0.f,0.f,0.f,0.f);
    *(float4*)(lds + i*4) = v;
  }
  __syncthreads();

  for (int u = tid; u < E_ROWS*32; u += 256){
    int row = u >> 5;
    int c8  = u & 31;
    int col = c8*8;
    s16x8 o;
    if (col + 8 <= ED){
      #pragma unroll
      for (int j2=0;j2<4;j2++){
        float2 f = *(const float2*)(lds + row*ED + col + j2*2);
        o[j2*2]   = f2bf(f.x);
        o[j2*2+1] = f2bf(f.y);
      }
    } else {
      #pragma unroll
      for (int j=0;j<8;j++){
        int c = col + j;
        o[j] = (c < ED) ? f2bf(lds[row*ED + c]) : (short)0;
      }
    }
    *(s16x8*)(eb + (size_t)(row0+row)*EDP + col) = o;
  }
}

// ---------------- fused weight prep: BOTH convs, one launch (162 blocks) ----
__global__ __launch_bounds__(256) void prep_weights_all(
    const float* __restrict__ Wq1, const float* __restrict__ Wk1,
    const float* __restrict__ Wv1, const float* __restrict__ Ws1,
    const float* __restrict__ We1,
    const float* __restrict__ bq1, const float* __restrict__ bk1,
    const float* __restrict__ bv1, const float* __restrict__ bs1,
    const float* __restrict__ Wq2, const float* __restrict__ Wk2,
    const float* __restrict__ Wv2, const float* __restrict__ Ws2,
    const float* __restrict__ We2,
    const float* __restrict__ bq2, const float* __restrict__ bk2,
    const float* __restrict__ bv2, const float* __restrict__ bs2,
    short* __restrict__ WtN1, short* __restrict__ WtN2,
    short* __restrict__ WtE, float* __restrict__ biasN1, float* __restrict__ biasN2)
{
  __shared__ short lds[64*65];
  int b = blockIdx.x, tid = threadIdx.x;
  if (b < 128){
    int conv = b>>6, bb = b&63;
    int mat = bb>>4, tile = bb&15;
    int i0 = (tile>>2)*64, o0 = (tile&3)*64;
    const float* W = conv ? ((mat==0)?Wq2:((mat==1)?Wk2:((mat==2)?Wv2:Ws2)))
                          : ((mat==0)?Wq1:((mat==1)?Wk1:((mat==2)?Wv1:Ws1)));
    short* WtN = conv ? WtN2 : WtN1;
    #pragma unroll
    for (int t=0;t<16;t++){
      int idx = t*256+tid; int r = idx>>6, c = idx&63;
      lds[r*65+c] = f2bf(W[(size_t)(i0+r)*256 + o0 + c]);
    }
    __syncthreads();
    #pragma unroll
    for (int t=0;t<4;t++){
      int idx = t*256+tid; int r = idx>>4, c4 = (idx&15)*4;
      s16x4 o;
      o[0]=lds[(c4+0)*65+r]; o[1]=lds[(c4+1)*65+r];
      o[2]=lds[(c4+2)*65+r]; o[3]=lds[(c4+3)*65+r];
      *(s16x4*)(WtN + (mat<<16) + (o0+r)*256 + i0 + c4) = o;
    }
  } else if (b < 160){
    int b2 = b-128;                 // 32 blocks: 4 k-tiles x 8 o-tiles
    int k0 = (b2>>3)*64, o0 = (b2&7)*64;   // o0 in 0..511, k0 in 0..192
    const float* We = (o0 < 256) ? We1 : We2;
    int oc = o0 & 255;
    #pragma unroll
    for (int t=0;t<16;t++){
      int idx = t*256+tid; int r = idx>>6, c = idx&63;
      int k = k0+r;
      lds[r*65+c] = (k<ED) ? f2bf(We[(size_t)k*256 + oc + c]) : (short)0;
    }
    __syncthreads();
    #pragma unroll
    for (int t=0;t<4;t++){
      int idx = t*256+tid; int r = idx>>4, c4 = (idx&15)*4;
      if (k0 + c4 < EDP){
        s16x4 o;
        o[0]=lds[(c4+0)*65+r]; o[1]=lds[(c4+1)*65+r];
        o[2]=lds[(c4+2)*65+r]; o[3]=lds[(c4+3)*65+r];
        *(s16x4*)(WtE + (size_t)(o0+r)*EDP + k0 + c4) = o;
      }
    }
  } else {
    int conv = b - 160;
    float* biasN = conv ? biasN2 : biasN1;
    for (int t = tid; t < 1024; t += 256){
      const float* bb = conv ? ((t<256)?bq2:((t<512)?bk2:((t<768)?bv2:bs2)))
                             : ((t<256)?bq1:((t<512)?bk1:((t<768)?bv1:bs1)));
      biasN[t] = bb[t&255];
    }
  }
}

// ---------------- CSR build ----------------
__global__ __launch_bounds__(256) void count_deg(const int* __restrict__ dst, int* __restrict__ deg){
  int e = blockIdx.x*256 + threadIdx.x;
  if (e < N_EDGES) atomicAdd(&deg[dst[e]], 1);
}
#define SCAN_NBLK 196
__global__ __launch_bounds__(256) void scan_p1(const int* __restrict__ deg, int* __restrict__ part){
  int t = threadIdx.x;
  int i = blockIdx.x*256 + t;
  int v = (i<N_NODES)? deg[i] : 0;
  #pragma unroll
  for (int off=32; off; off>>=1) v += __shfl_xor(v, off, 64);
  __shared__ int s[4];
  if ((t&63)==0) s[t>>6] = v;
  __syncthreads();
  if (t==0) part[blockIdx.x] = s[0]+s[1]+s[2]+s[3];
}
__global__ __launch_bounds__(256) void scan_p2(int* __restrict__ part){
  __shared__ int s[256];
  int t = threadIdx.x;
  int v = (t<SCAN_NBLK)? part[t] : 0;
  s[t] = v; __syncthreads();
  for (int off=1; off<256; off<<=1){
    int x = (t>=off)? s[t-off] : 0;
    __syncthreads();
    s[t] += x;
    __syncthreads();
  }
  part[t] = (t==0)? 0 : s[t-1];
}
// also zeroes cursor
__global__ __launch_bounds__(256) void scan_p3(const int* __restrict__ deg,
    const int* __restrict__ part, int* __restrict__ rowptr, int* __restrict__ cursor){
  __shared__ int s[256];
  int t = threadIdx.x;
  int i = blockIdx.x*256 + t;
  int v = (i<N_NODES)? deg[i] : 0;
  s[t] = v; __syncthreads();
  for (int off=1; off<256; off<<=1){
    int x = (t>=off)? s[t-off] : 0;
    __syncthreads();
    s[t] += x;
    __syncthreads();
  }
  if (i < N_NODES){ rowptr[i+1] = part[blockIdx.x] + s[t]; cursor[i] = 0; }
  if (i == 0) rowptr[0] = 0;
}
// csr entries premultiplied to byte offsets:
//   x = src*2048 (QKVS row), y = e*1024 (Eemb row, 512 bf16 cols for both convs)
__global__ __launch_bounds__(256) void scatter_edges(
    const int* __restrict__ src, const int* __restrict__ dst,
    const int* __restrict__ rowptr, int* __restrict__ cursor, int2* __restrict__ csr)
{
  int e = blockIdx.x*256 + threadIdx.x;
  if (e < N_EDGES){
    int d = dst[e];
    int pos = atomicAdd(&cursor[d], 1);
    csr[rowptr[d] + pos] = make_int2(src[e]<<11, e<<10);
  }
}

// ---------------- tiled GEMM: out = A(bf16,[Mpad][K]) @ Bt^T (Bt=[N][K] bf16) ----
// r13/r15-proven structure (the 812.6us base): 128x128 tile, 4 waves, BK=64,
// single-buffered LDS 32KB (4-5 blocks/CU — implicit wave-overlap does the
// latency hiding), within-row XOR chunk swizzle (conflicts 7M->0, r13),
// same-XCD A-sharing block swizzle for SWZ_NB>0 (r12: FETCH 245->57MB).
//   bid -> xcd=bid&7, w=bid>>3, n=w%NB, m=(w/NB)*8+xcd (+ linear tail).
// FINAL CONFIG — every neighboring variant measured worse:
//  r3 4-edge unroll, r4 128x256 tile, r5 fragment-major staging, r6 coop-CSR,
//  r7 perm-gather, r10 n-fastest grid + LDS swizzle alone, r11 NT stores,
//  r14 dbuf+counted-vmcnt (occupancy), r16 edge+node launch fusion (L2 dilute).
template<int K, int NLD, bool HAS_BIAS, int SWZ_NB>
__global__ __launch_bounds__(256) void gemm_bt(
    const short* __restrict__ A, const short* __restrict__ Bt,
    const float* __restrict__ bias, short* __restrict__ out, int M)
{
  __shared__ short As[128*64];   // 16 KB
  __shared__ short Bs[128*64];   // 16 KB
  int tid = threadIdx.x;
  int lane = tid & 63, wave = tid >> 6;

  int mblk, nblk;
  if (SWZ_NB > 0){
    int bid = blockIdx.x;
    int MB  = gridDim.x / SWZ_NB;
    int MB8 = MB & ~7;
    int body = MB8 * SWZ_NB;
    if (bid < body){
      int xcd = bid & 7, w = bid >> 3;
      nblk = w % SWZ_NB;
      mblk = (w / SWZ_NB) * 8 + xcd;
    } else {
      int r = bid - body;
      mblk = MB8 + r / SWZ_NB;
      nblk = r % SWZ_NB;
    }
  } else {
    mblk = blockIdx.x; nblk = blockIdx.y;
  }
  int m0 = mblk*128, n0 = nblk*128;

  // staging: wave w, lane l covers row w*8+(l>>3) (+ i*32 per instruction),
  // LDS chunk l&7; global source chunk (l&7)^((l>>3)&7)  [row&7 == (l>>3)&7]
  int srow = wave*8 + (lane>>3);
  int sx   = ((lane&7) ^ ((lane>>3)&7))*8;      // swizzled source col (shorts)
  const short* gA = A + (size_t)(m0+srow)*K + sx;
  const short* gB = Bt + (size_t)(n0+srow)*K + sx;
  short* ldsA = As + wave*512;                  // + i*2048 per instruction
  short* ldsB = Bs + wave*512;

  int wr = wave>>1, wc = wave&1;
  int fr = lane & 15;
  int kq = lane >> 4;
  int frx = fr & 7;
  const short* arb = As + (wr*64 + fr)*64;      // fragment row base (64-col rows)
  const short* brb = Bs + (wc*64 + fr)*64;

  f32x4 acc[4][4];
  #pragma unroll
  for (int a=0;a<4;a++)
    #pragma unroll
    for (int b=0;b<4;b++) acc[a][b] = (f32x4){0.f,0.f,0.f,0.f};

  for (int k0=0; k0<K; k0+=64){
    __syncthreads();
    #pragma unroll
    for (int i=0;i<4;i++){
      gload_lds16(gA + (size_t)i*32*K + k0, ldsA + i*2048);
      gload_lds16(gB + (size_t)i*32*K + k0, ldsB + i*2048);
    }
    __syncthreads();

    #pragma unroll
    for (int ks=0; ks<2; ks++){
      int cA = ((ks*4 + kq) ^ frx)*8;           // swizzled read chunk offset
      bf16x8 af[4], bf[4];
      #pragma unroll
      for (int fm=0;fm<4;fm++) af[fm] = *(const bf16x8*)(arb + fm*1024 + cA);
      #pragma unroll
      for (int fn=0;fn<4;fn++) bf[fn] = *(const bf16x8*)(brb + fn*1024 + cA);
      #pragma unroll
      for (int fm=0;fm<4;fm++)
        #pragma unroll
        for (int fn=0;fn<4;fn++)
          acc[fm][fn] = __builtin_amdgcn_mfma_f32_16x16x32_bf16(af[fm], bf[fn], acc[fm][fn], 0, 0, 0);
    }
  }

  int cr = (lane>>4)*4;
  int cc = lane & 15;
  #pragma unroll
  for (int fm=0;fm<4;fm++){
    #pragma unroll
    for (int fn=0;fn<4;fn++){
      int col = n0 + wc*64 + fn*16 + cc;
      float bv = HAS_BIAS ? bias[col] : 0.f;
      #pragma unroll
      for (int i=0;i<4;i++){
        int row = m0 + wr*64 + fm*16 + cr + i;
        if (row < M) out[(size_t)row*NLD + col] = f2bf(acc[fm][fn][i] + bv);
      }
    }
  }
}

// ---------------- fused edge phase ----------------
// ONE WAVE PER NODE (4 nodes per block, no __syncthreads, no LDS merge).
// 32 lanes per edge, 8 channels per lane (16B loads), TWO edges in flight
// (half = lane>>5). csr entry for the NEXT iteration software-prefetched.
// Eemb rows are 512 bf16 (both convs); caller passes base +0 (conv1) or +256.
__global__ __launch_bounds__(256) void edge_phase_kernel(
    const short* __restrict__ QKVS, const short* __restrict__ Eemb,
    const int* __restrict__ rowptr, const int2* __restrict__ csr,
    short* __restrict__ out_bf, float* __restrict__ out_f, int relu)
{
  int tid = threadIdx.x, wave = tid>>6, lane = tid&63;
  int node = blockIdx.x*4 + wave;
  if (node >= N_NODES){
    if (node < MP_NODE && out_bf){
      s16x4 z; z[0]=0; z[1]=0; z[2]=0; z[3]=0;
      *(s16x4*)(out_bf + (size_t)node*256 + lane*4) = z;
    }
    return;
  }
  int half = lane>>5;          // which edge of the pair
  int hl   = lane&31;          // channel-group 0..31 (8 ch each)
  int c8   = hl*8;
  const unsigned short* base = (const unsigned short*)QKVS + (size_t)node*1024;

  u16x8 qu = *(const u16x8*)(base + c8);
  float q[8];
  #pragma unroll
  for (int j=0;j<8;j++) q[j] = bf2f(qu[j])*0.125f;

  int beg = rowptr[node], end = rowptr[node+1];
  float l = 0.f;
  float a[8];
  #pragma unroll
  for (int j=0;j<8;j++) a[j] = 0.f;
  int kb = 512 + hl*16;        // K byte offset within QKVS row for this lane
  int ebo = hl*16;             // Eemb byte offset within row-half

  if (beg < end){
    int j0 = beg + half;
    int2 se = csr[(j0 < end) ? j0 : (end-1)];
    for (int idx = beg; idx < end; idx += 2){
      int jn = idx + 2 + half;
      int2 se_n = csr[(jn < end) ? jn : (end-1)];   // prefetch next iteration
      int j = idx + half;
      const char* Kp = (const char*)QKVS + (unsigned)(se.x + kb);
      const char* Ep = (const char*)Eemb + (unsigned)(se.y + ebo);
      u16x8 ku = *(const u16x8*)Kp;
      u16x8 vu = *(const u16x8*)(Kp + 512);   // V block
      u16x8 eu = *(const u16x8*)Ep;
      float vv[8];
      float t = 0.f;
      #pragma unroll
      for (int c=0;c<8;c++){
        float ef = bf2f(eu[c]);
        float kf = bf2f(ku[c]) + ef;
        vv[c]    = bf2f(vu[c]) + ef;
        t += q[c]*kf;
      }
      t += __shfl_xor(t, 1, 64);
      t += __shfl_xor(t, 2, 64);
      t += __shfl_xor(t, 4, 64);
      float p = (j < end) ? __expf(t) : 0.f;
      l += p;
      #pragma unroll
      for (int c=0;c<8;c++) a[c] += p*vv[c];
      se = se_n;
    }
  }

  // merge the two halves (each summed a disjoint subset of edges)
  l += __shfl_xor(l, 32, 64);
  #pragma unroll
  for (int c=0;c<8;c++) a[c] += __shfl_xor(a[c], 32, 64);

  float inv = (l > 0.f) ? 1.0f/l : 0.f;
  u16x8 su = *(const u16x8*)(base + 768 + c8);   // skip = x@Ws + bs
  float r[8];
  #pragma unroll
  for (int c=0;c<8;c++){
    float v = a[c]*inv + bf2f(su[c]);
    r[c] = relu ? fmaxf(v, 0.f) : v;
  }

  if (out_bf){
    if (!half){
      s16x8 o;
      #pragma unroll
      for (int c=0;c<8;c++) o[c] = f2bf(r[c]);
      *(s16x8*)(out_bf + (size_t)node*256 + c8) = o;
    }
  } else {
    float4 st = half ? make_float4(r[4],r[5],r[6],r[7])
                     : make_float4(r[0],r[1],r[2],r[3]);
    *(float4*)(out_f + (size_t)node*256 + c8 + half*4) = st;
  }
}

// ---------------- launch ----------------
extern "C" void kernel_launch(void* const* d_in, const int* in_sizes, int n_in,
                              void* d_out, int out_size, void* d_ws, size_t ws_size,
                              hipStream_t stream)
{
  const float* x     = (const float*)d_in[0];
  const int*   eidx  = (const int*)d_in[1];
  const float* eattr = (const float*)d_in[2];
  const float* Wq1=(const float*)d_in[3],  *bq1=(const float*)d_in[4];
  const float* Wk1=(const float*)d_in[5],  *bk1=(const float*)d_in[6];
  const float* Wv1=(const float*)d_in[7],  *bv1=(const float*)d_in[8];
  const float* We1=(const float*)d_in[9];
  const float* Ws1=(const float*)d_in[10], *bs1=(const float*)d_in[11];
  const float* Wq2=(const float*)d_in[12], *bq2=(const float*)d_in[13];
  const float* Wk2=(const float*)d_in[14], *bk2=(const float*)d_in[15];
  const float* Wv2=(const float*)d_in[16], *bv2=(const float*)d_in[17];
  const float* We2=(const float*)d_in[18];
  const float* Ws2=(const float*)d_in[19], *bs2=(const float*)d_in[20];

  char* ws = (char*)d_ws;
  size_t off = 0;
  auto alloc = [&](size_t bytes)->char*{
    char* p = ws + off; off = (off + bytes + 255) & ~(size_t)255; return p;
  };
  short* QKVS  = (short*)alloc((size_t)N_NODES*1024*2);
  short* Eemb  = (short*)alloc((size_t)MP_EDGE*512*2);   // 512 cols: conv1|conv2
  short* x_bf  = (short*)alloc((size_t)MP_NODE*DIM*2);
  short* h_bf  = (short*)alloc((size_t)MP_NODE*DIM*2);
  short* e_bf  = (short*)alloc((size_t)MP_EDGE*EDP*2);   // K padded to 256
  short* WtN1  = (short*)alloc((size_t)4*65536*2);
  short* WtN2  = (short*)alloc((size_t)4*65536*2);
  short* WtE   = (short*)alloc((size_t)512*EDP*2);
  float* biasN1= (float*)alloc((size_t)1024*4);
  float* biasN2= (float*)alloc((size_t)1024*4);
  int*   deg   = (int*)alloc((size_t)N_NODES*4);
  int*   rowptr= (int*)alloc((size_t)(N_NODES+1)*4);
  int*   cursor= (int*)alloc((size_t)N_NODES*4);
  int*   part  = (int*)alloc((size_t)256*4);
  int2*  csr   = (int2*)alloc((size_t)N_EDGES*8);

  const int* srcp = eidx;
  const int* dstp = eidx + N_EDGES;

  const int EB = (N_EDGES + 255)/256;   // 977

  convert_x_kernel<<<MP_NODE*64/256,256,0,stream>>>(x, x_bf, deg);
  convert_e_kernel<<<MP_EDGE/E_ROWS,256,0,stream>>>(eattr, e_bf);

  count_deg<<<EB,256,0,stream>>>(dstp, deg);
  scan_p1<<<SCAN_NBLK,256,0,stream>>>(deg, part);
  scan_p2<<<1,256,0,stream>>>(part);
  scan_p3<<<SCAN_NBLK,256,0,stream>>>(deg, part, rowptr, cursor);
  scatter_edges<<<EB,256,0,stream>>>(srcp, dstp, rowptr, cursor, csr);

  prep_weights_all<<<162,256,0,stream>>>(
      Wq1,Wk1,Wv1,Ws1,We1,bq1,bk1,bv1,bs1,
      Wq2,Wk2,Wv2,Ws2,We2,bq2,bk2,bv2,bs2,
      WtN1,WtN2,WtE,biasN1,biasN2);

  // merged edge GEMM: Eemb[:,0:256]=e@We1, [:,256:512]=e@We2 — e_bf read ONCE.
  // 1D grid + same-XCD A-sharing swizzle (r12: FETCH 245->57MB).
  gemm_bt<EDP,512,false,4><<<(MP_EDGE/128)*4,256,0,stream>>>(e_bf, WtE, nullptr, Eemb, N_EDGES);

  // ---- conv1 ---- (node GEMM: same-XCD swizzle too, 8 sharers per A-panel)
  gemm_bt<DIM,1024,true,8><<<(MP_NODE/128)*8,256,0,stream>>>(x_bf, WtN1, biasN1, QKVS, N_NODES);
  edge_phase_kernel<<<MP_NODE/4,256,0,stream>>>(QKVS,Eemb,rowptr,csr,h_bf,nullptr,1);

  // ---- conv2 ----
  gemm_bt<DIM,1024,true,8><<<(MP_NODE/128)*8,256,0,stream>>>(h_bf, WtN2, biasN2, QKVS, N_NODES);
  edge_phase_kernel<<<N_NODES/4,256,0,stream>>>(QKVS,Eemb+256,rowptr,csr,nullptr,(float*)d_out,0);
}

// Round 18
// 776.256 us; speedup vs baseline: 1.0807x; 1.0418x over previous
//
#include <hip/hip_runtime.h>

#define N_NODES 50000
#define N_EDGES 250000
#define DIM 256          // IN = OUT = H*C
#define ED 194           // edge feature dim
#define EDP 256          // edge K padded to BK=64 multiple
#define MP_NODE 50048    // 391*128
#define MP_EDGE 250112   // 1954*128

typedef __bf16 bf16x8 __attribute__((ext_vector_type(8)));
typedef float f32x4 __attribute__((ext_vector_type(4)));
typedef short s16x8 __attribute__((ext_vector_type(8)));
typedef short s16x4 __attribute__((ext_vector_type(4)));
typedef unsigned short u16x8 __attribute__((ext_vector_type(8)));

__device__ __forceinline__ float bf2f(unsigned short b){
  union { unsigned int u; float f; } v; v.u = ((unsigned int)b)<<16; return v.f;
}
__device__ __forceinline__ short f2bf(float f){
  union { float f; unsigned int u; } v; v.f = f;
  unsigned int u = v.u;
  return (short)((u + 0x7fffu + ((u>>16)&1u))>>16);
}

// async global->LDS, 16B per lane. LDS dest = wave-uniform base + lane*16.
__device__ __forceinline__ void gload_lds16(const void* g, void* l){
  __builtin_amdgcn_global_load_lds(
      (const __attribute__((address_space(1))) unsigned int*)g,
      (__attribute__((address_space(3))) unsigned int*)l, 16, 0, 0);
}

// ---------------- input converts (fp32 -> bf16, padded) ----------------
__global__ __launch_bounds__(256) void convert_x_kernel(
    const float* __restrict__ x, short* __restrict__ xb, int* __restrict__ deg)
{
  int idx = blockIdx.x*256 + threadIdx.x;       // MP_NODE*64 float4s total
  if (idx < N_NODES) deg[idx] = 0;
  s16x4 o;
  if (idx < N_NODES*64){
    float4 a = *(const float4*)(x + (size_t)idx*4);
    o[0]=f2bf(a.x); o[1]=f2bf(a.y); o[2]=f2bf(a.z); o[3]=f2bf(a.w);
  } else {
    o[0]=0; o[1]=0; o[2]=0; o[3]=0;
  }
  *(s16x4*)(xb + (size_t)idx*4) = o;
}

// Edge rows are 194 floats (776B) -> stage 32 rows through LDS with dense
// flat float4 loads, then convert+pad (to EDP=256) with coalesced stores.
#define E_ROWS 32
__global__ __launch_bounds__(256) void convert_e_kernel(
    const float* __restrict__ ea, short* __restrict__ eb)
{
  __shared__ float lds[E_ROWS*ED];              // 6208 floats = 24832 B
  int row0 = blockIdx.x * E_ROWS;
  int tid = threadIdx.x;
  int base = row0 * ED;                         // float index of block start
  int valid = N_EDGES*ED - base;                // may be <=0 for pad blocks

  for (int i = tid; i < E_ROWS*ED/4; i += 256){
    float4 v;
    if (i*4 < valid) v = *(const float4*)(ea + base + i*4);
    else             v = make_float4(0.f,0.f,0.f,0.f);
    *(float4*)(lds + i*4) = v;
  }
  __syncthreads();

  for (int u = tid; u < E_ROWS*32; u += 256){
    int row = u >> 5;
    int c8  = u & 31;
    int col = c8*8;
    s16x8 o;
    if (col + 8 <= ED){
      #pragma unroll
      for (int j2=0;j2<4;j2++){
        float2 f = *(const float2*)(lds + row*ED + col + j2*2);
        o[j2*2]   = f2bf(f.x);
        o[j2*2+1] = f2bf(f.y);
      }
    } else {
      #pragma unroll
      for (int j=0;j<8;j++){
        int c = col + j;
        o[j] = (c < ED) ? f2bf(lds[row*ED + c]) : (short)0;
      }
    }
    *(s16x8*)(eb + (size_t)(row0+row)*EDP + col) = o;
  }
}

// ---------------- fused weight prep: BOTH convs, one launch (162 blocks) ----
__global__ __launch_bounds__(256) void prep_weights_all(
    const float* __restrict__ Wq1, const float* __restrict__ Wk1,
    const float* __restrict__ Wv1, const float* __restrict__ Ws1,
    const float* __restrict__ We1,
    const float* __restrict__ bq1, const float* __restrict__ bk1,
    const float* __restrict__ bv1, const float* __restrict__ bs1,
    const float* __restrict__ Wq2, const float* __restrict__ Wk2,
    const float* __restrict__ Wv2, const float* __restrict__ Ws2,
    const float* __restrict__ We2,
    const float* __restrict__ bq2, const float* __restrict__ bk2,
    const float* __restrict__ bv2, const float* __restrict__ bs2,
    short* __restrict__ WtN1, short* __restrict__ WtN2,
    short* __restrict__ WtE, float* __restrict__ biasN1, float* __restrict__ biasN2)
{
  __shared__ short lds[64*65];
  int b = blockIdx.x, tid = threadIdx.x;
  if (b < 128){
    int conv = b>>6, bb = b&63;
    int mat = bb>>4, tile = bb&15;
    int i0 = (tile>>2)*64, o0 = (tile&3)*64;
    const float* W = conv ? ((mat==0)?Wq2:((mat==1)?Wk2:((mat==2)?Wv2:Ws2)))
                          : ((mat==0)?Wq1:((mat==1)?Wk1:((mat==2)?Wv1:Ws1)));
    short* WtN = conv ? WtN2 : WtN1;
    #pragma unroll
    for (int t=0;t<16;t++){
      int idx = t*256+tid; int r = idx>>6, c = idx&63;
      lds[r*65+c] = f2bf(W[(size_t)(i0+r)*256 + o0 + c]);
    }
    __syncthreads();
    #pragma unroll
    for (int t=0;t<4;t++){
      int idx = t*256+tid; int r = idx>>4, c4 = (idx&15)*4;
      s16x4 o;
      o[0]=lds[(c4+0)*65+r]; o[1]=lds[(c4+1)*65+r];
      o[2]=lds[(c4+2)*65+r]; o[3]=lds[(c4+3)*65+r];
      *(s16x4*)(WtN + (mat<<16) + (o0+r)*256 + i0 + c4) = o;
    }
  } else if (b < 160){
    int b2 = b-128;                 // 32 blocks: 4 k-tiles x 8 o-tiles
    int k0 = (b2>>3)*64, o0 = (b2&7)*64;   // o0 in 0..511, k0 in 0..192
    const float* We = (o0 < 256) ? We1 : We2;
    int oc = o0 & 255;
    #pragma unroll
    for (int t=0;t<16;t++){
      int idx = t*256+tid; int r = idx>>6, c = idx&63;
      int k = k0+r;
      lds[r*65+c] = (k<ED) ? f2bf(We[(size_t)k*256 + oc + c]) : (short)0;
    }
    __syncthreads();
    #pragma unroll
    for (int t=0;t<4;t++){
      int idx = t*256+tid; int r = idx>>4, c4 = (idx&15)*4;
      if (k0 + c4 < EDP){
        s16x4 o;
        o[0]=lds[(c4+0)*65+r]; o[1]=lds[(c4+1)*65+r];
        o[2]=lds[(c4+2)*65+r]; o[3]=lds[(c4+3)*65+r];
        *(s16x4*)(WtE + (size_t)(o0+r)*EDP + k0 + c4) = o;
      }
    }
  } else {
    int conv = b - 160;
    float* biasN = conv ? biasN2 : biasN1;
    for (int t = tid; t < 1024; t += 256){
      const float* bb = conv ? ((t<256)?bq2:((t<512)?bk2:((t<768)?bv2:bs2)))
                             : ((t<256)?bq1:((t<512)?bk1:((t<768)?bv1:bs1)));
      biasN[t] = bb[t&255];
    }
  }
}

// ---------------- CSR build ----------------
__global__ __launch_bounds__(256) void count_deg(const int* __restrict__ dst, int* __restrict__ deg){
  int e = blockIdx.x*256 + threadIdx.x;
  if (e < N_EDGES) atomicAdd(&deg[dst[e]], 1);
}
#define SCAN_NBLK 196
__global__ __launch_bounds__(256) void scan_p1(const int* __restrict__ deg, int* __restrict__ part){
  int t = threadIdx.x;
  int i = blockIdx.x*256 + t;
  int v = (i<N_NODES)? deg[i] : 0;
  #pragma unroll
  for (int off=32; off; off>>=1) v += __shfl_xor(v, off, 64);
  __shared__ int s[4];
  if ((t&63)==0) s[t>>6] = v;
  __syncthreads();
  if (t==0) part[blockIdx.x] = s[0]+s[1]+s[2]+s[3];
}
__global__ __launch_bounds__(256) void scan_p2(int* __restrict__ part){
  __shared__ int s[256];
  int t = threadIdx.x;
  int v = (t<SCAN_NBLK)? part[t] : 0;
  s[t] = v; __syncthreads();
  for (int off=1; off<256; off<<=1){
    int x = (t>=off)? s[t-off] : 0;
    __syncthreads();
    s[t] += x;
    __syncthreads();
  }
  part[t] = (t==0)? 0 : s[t-1];
}
// also zeroes cursor
__global__ __launch_bounds__(256) void scan_p3(const int* __restrict__ deg,
    const int* __restrict__ part, int* __restrict__ rowptr, int* __restrict__ cursor){
  __shared__ int s[256];
  int t = threadIdx.x;
  int i = blockIdx.x*256 + t;
  int v = (i<N_NODES)? deg[i] : 0;
  s[t] = v; __syncthreads();
  for (int off=1; off<256; off<<=1){
    int x = (t>=off)? s[t-off] : 0;
    __syncthreads();
    s[t] += x;
    __syncthreads();
  }
  if (i < N_NODES){ rowptr[i+1] = part[blockIdx.x] + s[t]; cursor[i] = 0; }
  if (i == 0) rowptr[0] = 0;
}
// csr entries premultiplied to byte offsets:
//   x = src*2048 (QKVS row), y = e*1024 (Eemb row, 512 bf16 cols for both convs)
__global__ __launch_bounds__(256) void scatter_edges(
    const int* __restrict__ src, const int* __restrict__ dst,
    const int* __restrict__ rowptr, int* __restrict__ cursor, int2* __restrict__ csr)
{
  int e = blockIdx.x*256 + threadIdx.x;
  if (e < N_EDGES){
    int d = dst[e];
    int pos = atomicAdd(&cursor[d], 1);
    csr[rowptr[d] + pos] = make_int2(src[e]<<11, e<<10);
  }
}

// ---------------- tiled GEMM: out = A(bf16,[Mpad][K]) @ Bt^T (Bt=[N][K] bf16) ----
// r13/r15-proven structure (the 808.7us base): 128x128 tile, 4 waves, BK=64,
// single-buffered LDS 32KB, within-row XOR chunk swizzle (conflicts 7M->0),
// same-XCD A-sharing block swizzle (r12: FETCH 245->57MB).
// r18: WIDE EPILOGUE — old epilogue issued 64 global_store_short (2B) per
// thread (2/3 of all VMEM issues, uncovered serial tail). Now C routes through
// the dead LDS staging buffers: per 16-row fm block, scattered ds_write_b16
// into a 72-short-padded tile (2-way bank alias = free; 144B row stride makes
// readback conflict-free), then 2 x {ds_read_b128 + global_store_dwordx4}
// per fm -> 8 wide stores/thread, 128B-dense write bursts.
// (r14 dbuf REGRESSED: occupancy. r16 launch fusion REGRESSED: L2 dilution.
//  r11 NT stores: WRITE 2x. r10 n-fastest: cross-XCD. r4/r5: tile/staging.)
template<int K, int NLD, bool HAS_BIAS, int SWZ_NB>
__global__ __launch_bounds__(256) void gemm_bt(
    const short* __restrict__ A, const short* __restrict__ Bt,
    const float* __restrict__ bias, short* __restrict__ out, int M)
{
  __shared__ short As[128*64];   // 16 KB
  __shared__ short Bs[128*64];   // 16 KB
  int tid = threadIdx.x;
  int lane = tid & 63, wave = tid >> 6;

  int mblk, nblk;
  if (SWZ_NB > 0){
    int bid = blockIdx.x;
    int MB  = gridDim.x / SWZ_NB;
    int MB8 = MB & ~7;
    int body = MB8 * SWZ_NB;
    if (bid < body){
      int xcd = bid & 7, w = bid >> 3;
      nblk = w % SWZ_NB;
      mblk = (w / SWZ_NB) * 8 + xcd;
    } else {
      int r = bid - body;
      mblk = MB8 + r / SWZ_NB;
      nblk = r % SWZ_NB;
    }
  } else {
    mblk = blockIdx.x; nblk = blockIdx.y;
  }
  int m0 = mblk*128, n0 = nblk*128;

  // staging: wave w, lane l covers row w*8+(l>>3) (+ i*32 per instruction),
  // LDS chunk l&7; global source chunk (l&7)^((l>>3)&7)  [row&7 == (l>>3)&7]
  int srow = wave*8 + (lane>>3);
  int sx   = ((lane&7) ^ ((lane>>3)&7))*8;      // swizzled source col (shorts)
  const short* gA = A + (size_t)(m0+srow)*K + sx;
  const short* gB = Bt + (size_t)(n0+srow)*K + sx;
  short* ldsA = As + wave*512;                  // + i*2048 per instruction
  short* ldsB = Bs + wave*512;

  int wr = wave>>1, wc = wave&1;
  int fr = lane & 15;
  int kq = lane >> 4;
  int frx = fr & 7;
  const short* arb = As + (wr*64 + fr)*64;      // fragment row base (64-col rows)
  const short* brb = Bs + (wc*64 + fr)*64;

  f32x4 acc[4][4];
  #pragma unroll
  for (int a=0;a<4;a++)
    #pragma unroll
    for (int b=0;b<4;b++) acc[a][b] = (f32x4){0.f,0.f,0.f,0.f};

  for (int k0=0; k0<K; k0+=64){
    __syncthreads();
    #pragma unroll
    for (int i=0;i<4;i++){
      gload_lds16(gA + (size_t)i*32*K + k0, ldsA + i*2048);
      gload_lds16(gB + (size_t)i*32*K + k0, ldsB + i*2048);
    }
    __syncthreads();

    #pragma unroll
    for (int ks=0; ks<2; ks++){
      int cA = ((ks*4 + kq) ^ frx)*8;           // swizzled read chunk offset
      bf16x8 af[4], bf[4];
      #pragma unroll
      for (int fm=0;fm<4;fm++) af[fm] = *(const bf16x8*)(arb + fm*1024 + cA);
      #pragma unroll
      for (int fn=0;fn<4;fn++) bf[fn] = *(const bf16x8*)(brb + fn*1024 + cA);
      #pragma unroll
      for (int fm=0;fm<4;fm++)
        #pragma unroll
        for (int fn=0;fn<4;fn++)
          acc[fm][fn] = __builtin_amdgcn_mfma_f32_16x16x32_bf16(af[fm], bf[fn], acc[fm][fn], 0, 0, 0);
    }
  }

  // ---- wide epilogue via LDS round-trip ----
  __syncthreads();                // no wave still reads As/Bs fragments
  short* E = (wave < 2) ? (As + wave*4096) : (Bs + (wave-2)*4096);  // 8KB/wave
  int cr = (lane>>4)*4;
  int cc = lane & 15;
  int er  = lane>>3;              // 0..7
  int ec8 = (lane&7)*8;           // 0..56 shorts (16B chunks)
  int colbase = n0 + wc*64;
  #pragma unroll
  for (int fm=0;fm<4;fm++){
    #pragma unroll
    for (int fn=0;fn<4;fn++){
      float bv = HAS_BIAS ? bias[colbase + fn*16 + cc] : 0.f;
      #pragma unroll
      for (int i=0;i<4;i++)
        E[(cr+i)*72 + fn*16 + cc] = f2bf(acc[fm][fn][i] + bv);
    }
    #pragma unroll
    for (int rr=0; rr<2; rr++){
      int r = rr*8 + er;
      int row = m0 + wr*64 + fm*16 + r;
      s16x8 v = *(const s16x8*)(E + r*72 + ec8);
      if (row < M)
        *(s16x8*)(out + (size_t)row*NLD + colbase + ec8) = v;
    }
  }
}

// ---------------- fused edge phase ----------------
// ONE WAVE PER NODE (4 nodes per block, no __syncthreads, no LDS merge).
// 32 lanes per edge, 8 channels per lane (16B loads), TWO edges in flight
// (half = lane>>5). csr entry for the NEXT iteration software-prefetched.
// Eemb rows are 512 bf16 (both convs); caller passes base +0 (conv1) or +256.
__global__ __launch_bounds__(256) void edge_phase_kernel(
    const short* __restrict__ QKVS, const short* __restrict__ Eemb,
    const int* __restrict__ rowptr, const int2* __restrict__ csr,
    short* __restrict__ out_bf, float* __restrict__ out_f, int relu)
{
  int tid = threadIdx.x, wave = tid>>6, lane = tid&63;
  int node = blockIdx.x*4 + wave;
  if (node >= N_NODES){
    if (node < MP_NODE && out_bf){
      s16x4 z; z[0]=0; z[1]=0; z[2]=0; z[3]=0;
      *(s16x4*)(out_bf + (size_t)node*256 + lane*4) = z;
    }
    return;
  }
  int half = lane>>5;          // which edge of the pair
  int hl   = lane&31;          // channel-group 0..31 (8 ch each)
  int c8   = hl*8;
  const unsigned short* base = (const unsigned short*)QKVS + (size_t)node*1024;

  u16x8 qu = *(const u16x8*)(base + c8);
  float q[8];
  #pragma unroll
  for (int j=0;j<8;j++) q[j] = bf2f(qu[j])*0.125f;

  int beg = rowptr[node], end = rowptr[node+1];
  float l = 0.f;
  float a[8];
  #pragma unroll
  for (int j=0;j<8;j++) a[j] = 0.f;
  int kb = 512 + hl*16;        // K byte offset within QKVS row for this lane
  int ebo = hl*16;             // Eemb byte offset within row-half

  if (beg < end){
    int j0 = beg + half;
    int2 se = csr[(j0 < end) ? j0 : (end-1)];
    for (int idx = beg; idx < end; idx += 2){
      int jn = idx + 2 + half;
      int2 se_n = csr[(jn < end) ? jn : (end-1)];   // prefetch next iteration
      int j = idx + half;
      const char* Kp = (const char*)QKVS + (unsigned)(se.x + kb);
      const char* Ep = (const char*)Eemb + (unsigned)(se.y + ebo);
      u16x8 ku = *(const u16x8*)Kp;
      u16x8 vu = *(const u16x8*)(Kp + 512);   // V block
      u16x8 eu = *(const u16x8*)Ep;
      float vv[8];
      float t = 0.f;
      #pragma unroll
      for (int c=0;c<8;c++){
        float ef = bf2f(eu[c]);
        float kf = bf2f(ku[c]) + ef;
        vv[c]    = bf2f(vu[c]) + ef;
        t += q[c]*kf;
      }
      t += __shfl_xor(t, 1, 64);
      t += __shfl_xor(t, 2, 64);
      t += __shfl_xor(t, 4, 64);
      float p = (j < end) ? __expf(t) : 0.f;
      l += p;
      #pragma unroll
      for (int c=0;c<8;c++) a[c] += p*vv[c];
      se = se_n;
    }
  }

  // merge the two halves (each summed a disjoint subset of edges)
  l += __shfl_xor(l, 32, 64);
  #pragma unroll
  for (int c=0;c<8;c++) a[c] += __shfl_xor(a[c], 32, 64);

  float inv = (l > 0.f) ? 1.0f/l : 0.f;
  u16x8 su = *(const u16x8*)(base + 768 + c8);   // skip = x@Ws + bs
  float r[8];
  #pragma unroll
  for (int c=0;c<8;c++){
    float v = a[c]*inv + bf2f(su[c]);
    r[c] = relu ? fmaxf(v, 0.f) : v;
  }

  if (out_bf){
    if (!half){
      s16x8 o;
      #pragma unroll
      for (int c=0;c<8;c++) o[c] = f2bf(r[c]);
      *(s16x8*)(out_bf + (size_t)node*256 + c8) = o;
    }
  } else {
    float4 st = half ? make_float4(r[4],r[5],r[6],r[7])
                     : make_float4(r[0],r[1],r[2],r[3]);
    *(float4*)(out_f + (size_t)node*256 + c8 + half*4) = st;
  }
}

// ---------------- launch ----------------
extern "C" void kernel_launch(void* const* d_in, const int* in_sizes, int n_in,
                              void* d_out, int out_size, void* d_ws, size_t ws_size,
                              hipStream_t stream)
{
  const float* x     = (const float*)d_in[0];
  const int*   eidx  = (const int*)d_in[1];
  const float* eattr = (const float*)d_in[2];
  const float* Wq1=(const float*)d_in[3],  *bq1=(const float*)d_in[4];
  const float* Wk1=(const float*)d_in[5],  *bk1=(const float*)d_in[6];
  const float* Wv1=(const float*)d_in[7],  *bv1=(const float*)d_in[8];
  const float* We1=(const float*)d_in[9];
  const float* Ws1=(const float*)d_in[10], *bs1=(const float*)d_in[11];
  const float* Wq2=(const float*)d_in[12], *bq2=(const float*)d_in[13];
  const float* Wk2=(const float*)d_in[14], *bk2=(const float*)d_in[15];
  const float* Wv2=(const float*)d_in[16], *bv2=(const float*)d_in[17];
  const float* We2=(const float*)d_in[18];
  const float* Ws2=(const float*)d_in[19], *bs2=(const float*)d_in[20];

  char* ws = (char*)d_ws;
  size_t off = 0;
  auto alloc = [&](size_t bytes)->char*{
    char* p = ws + off; off = (off + bytes + 255) & ~(size_t)255; return p;
  };
  short* QKVS  = (short*)alloc((size_t)N_NODES*1024*2);
  short* Eemb  = (short*)alloc((size_t)MP_EDGE*512*2);   // 512 cols: conv1|conv2
  short* x_bf  = (short*)alloc((size_t)MP_NODE*DIM*2);
  short* h_bf  = (short*)alloc((size_t)MP_NODE*DIM*2);
  short* e_bf  = (short*)alloc((size_t)MP_EDGE*EDP*2);   // K padded to 256
  short* WtN1  = (short*)alloc((size_t)4*65536*2);
  short* WtN2  = (short*)alloc((size_t)4*65536*2);
  short* WtE   = (short*)alloc((size_t)512*EDP*2);
  float* biasN1= (float*)alloc((size_t)1024*4);
  float* biasN2= (float*)alloc((size_t)1024*4);
  int*   deg   = (int*)alloc((size_t)N_NODES*4);
  int*   rowptr= (int*)alloc((size_t)(N_NODES+1)*4);
  int*   cursor= (int*)alloc((size_t)N_NODES*4);
  int*   part  = (int*)alloc((size_t)256*4);
  int2*  csr   = (int2*)alloc((size_t)N_EDGES*8);

  const int* srcp = eidx;
  const int* dstp = eidx + N_EDGES;

  const int EB = (N_EDGES + 255)/256;   // 977

  convert_x_kernel<<<MP_NODE*64/256,256,0,stream>>>(x, x_bf, deg);
  convert_e_kernel<<<MP_EDGE/E_ROWS,256,0,stream>>>(eattr, e_bf);

  count_deg<<<EB,256,0,stream>>>(dstp, deg);
  scan_p1<<<SCAN_NBLK,256,0,stream>>>(deg, part);
  scan_p2<<<1,256,0,stream>>>(part);
  scan_p3<<<SCAN_NBLK,256,0,stream>>>(deg, part, rowptr, cursor);
  scatter_edges<<<EB,256,0,stream>>>(srcp, dstp, rowptr, cursor, csr);

  prep_weights_all<<<162,256,0,stream>>>(
      Wq1,Wk1,Wv1,Ws1,We1,bq1,bk1,bv1,bs1,
      Wq2,Wk2,Wv2,Ws2,We2,bq2,bk2,bv2,bs2,
      WtN1,WtN2,WtE,biasN1,biasN2);

  // merged edge GEMM: Eemb[:,0:256]=e@We1, [:,256:512]=e@We2 — e_bf read ONCE.
  // 1D grid + same-XCD A-sharing swizzle (r12: FETCH 245->57MB).
  gemm_bt<EDP,512,false,4><<<(MP_EDGE/128)*4,256,0,stream>>>(e_bf, WtE, nullptr, Eemb, N_EDGES);

  // ---- conv1 ---- (node GEMM: same-XCD swizzle too, 8 sharers per A-panel)
  gemm_bt<DIM,1024,true,8><<<(MP_NODE/128)*8,256,0,stream>>>(x_bf, WtN1, biasN1, QKVS, N_NODES);
  edge_phase_kernel<<<MP_NODE/4,256,0,stream>>>(QKVS,Eemb,rowptr,csr,h_bf,nullptr,1);

  // ---- conv2 ----
  gemm_bt<DIM,1024,true,8><<<(MP_NODE/128)*8,256,0,stream>>>(h_bf, WtN2, biasN2, QKVS, N_NODES);
  edge_phase_kernel<<<N_NODES/4,256,0,stream>>>(QKVS,Eemb+256,rowptr,csr,nullptr,(float*)d_out,0);
}

// Round 19
// 766.696 us; speedup vs baseline: 1.0942x; 1.0125x over previous
//
#include <hip/hip_runtime.h>

#define N_NODES 50000
#define N_EDGES 250000
#define DIM 256          // IN = OUT = H*C
#define ED 194           // edge feature dim
#define EDP 256          // edge K padded to BK=64 multiple
#define MP_NODE 50048    // 391*128
#define MP_EDGE 250112   // 1954*128

typedef __bf16 bf16x8 __attribute__((ext_vector_type(8)));
typedef float f32x4 __attribute__((ext_vector_type(4)));
typedef short s16x8 __attribute__((ext_vector_type(8)));
typedef short s16x4 __attribute__((ext_vector_type(4)));
typedef unsigned short u16x8 __attribute__((ext_vector_type(8)));

__device__ __forceinline__ float bf2f(unsigned short b){
  union { unsigned int u; float f; } v; v.u = ((unsigned int)b)<<16; return v.f;
}
__device__ __forceinline__ short f2bf(float f){
  union { float f; unsigned int u; } v; v.f = f;
  unsigned int u = v.u;
  return (short)((u + 0x7fffu + ((u>>16)&1u))>>16);
}

// async global->LDS, 16B per lane. LDS dest = wave-uniform base + lane*16.
__device__ __forceinline__ void gload_lds16(const void* g, void* l){
  __builtin_amdgcn_global_load_lds(
      (const __attribute__((address_space(1))) unsigned int*)g,
      (__attribute__((address_space(3))) unsigned int*)l, 16, 0, 0);
}

// ---------------- input converts (fp32 -> bf16, padded) ----------------
// Also zeroes deg[] (count_deg runs later in-stream inside convert_e).
__global__ __launch_bounds__(256) void convert_x_kernel(
    const float* __restrict__ x, short* __restrict__ xb, int* __restrict__ deg)
{
  int idx = blockIdx.x*256 + threadIdx.x;       // MP_NODE*64 float4s total
  if (idx < N_NODES) deg[idx] = 0;
  s16x4 o;
  if (idx < N_NODES*64){
    float4 a = *(const float4*)(x + (size_t)idx*4);
    o[0]=f2bf(a.x); o[1]=f2bf(a.y); o[2]=f2bf(a.z); o[3]=f2bf(a.w);
  } else {
    o[0]=0; o[1]=0; o[2]=0; o[3]=0;
  }
  *(s16x4*)(xb + (size_t)idx*4) = o;
}

// Edge rows are 194 floats (776B) -> stage 32 rows through LDS with dense
// flat float4 loads, then convert+pad (to EDP=256) with coalesced stores.
// r19: ALSO does count_deg for its 32 edges (1 atomic/edge, hidden under the
// HBM-saturated float streams; deg zeroed by convert_x which completes first
// on the in-order stream). Saves the separate count_deg launch.
#define E_ROWS 32
__global__ __launch_bounds__(256) void convert_e_kernel(
    const float* __restrict__ ea, short* __restrict__ eb,
    const int* __restrict__ dst, int* __restrict__ deg)
{
  __shared__ float lds[E_ROWS*ED];              // 6208 floats = 24832 B
  int row0 = blockIdx.x * E_ROWS;
  int tid = threadIdx.x;
  if (tid < E_ROWS){
    int e = row0 + tid;
    if (e < N_EDGES) atomicAdd(&deg[dst[e]], 1);
  }
  int base = row0 * ED;                         // float index of block start
  int valid = N_EDGES*ED - base;                // may be <=0 for pad blocks

  for (int i = tid; i < E_ROWS*ED/4; i += 256){
    float4 v;
    if (i*4 < valid) v = *(const float4*)(ea + base + i*4);
    else             v = make_float4(0.f,0.f,0.f,0.f);
    *(float4*)(lds + i*4) = v;
  }
  __syncthreads();

  for (int u = tid; u < E_ROWS*32; u += 256){
    int row = u >> 5;
    int c8  = u & 31;
    int col = c8*8;
    s16x8 o;
    if (col + 8 <= ED){
      #pragma unroll
      for (int j2=0;j2<4;j2++){
        float2 f = *(const float2*)(lds + row*ED + col + j2*2);
        o[j2*2]   = f2bf(f.x);
        o[j2*2+1] = f2bf(f.y);
      }
    } else {
      #pragma unroll
      for (int j=0;j<8;j++){
        int c = col + j;
        o[j] = (c < ED) ? f2bf(lds[row*ED + c]) : (short)0;
      }
    }
    *(s16x8*)(eb + (size_t)(row0+row)*EDP + col) = o;
  }
}

// ---------------- fused weight prep: BOTH convs, one launch (162 blocks) ----
__global__ __launch_bounds__(256) void prep_weights_all(
    const float* __restrict__ Wq1, const float* __restrict__ Wk1,
    const float* __restrict__ Wv1, const float* __restrict__ Ws1,
    const float* __restrict__ We1,
    const float* __restrict__ bq1, const float* __restrict__ bk1,
    const float* __restrict__ bv1, const float* __restrict__ bs1,
    const float* __restrict__ Wq2, const float* __restrict__ Wk2,
    const float* __restrict__ Wv2, const float* __restrict__ Ws2,
    const float* __restrict__ We2,
    const float* __restrict__ bq2, const float* __restrict__ bk2,
    const float* __restrict__ bv2, const float* __restrict__ bs2,
    short* __restrict__ WtN1, short* __restrict__ WtN2,
    short* __restrict__ WtE, float* __restrict__ biasN1, float* __restrict__ biasN2)
{
  __shared__ short lds[64*65];
  int b = blockIdx.x, tid = threadIdx.x;
  if (b < 128){
    int conv = b>>6, bb = b&63;
    int mat = bb>>4, tile = bb&15;
    int i0 = (tile>>2)*64, o0 = (tile&3)*64;
    const float* W = conv ? ((mat==0)?Wq2:((mat==1)?Wk2:((mat==2)?Wv2:Ws2)))
                          : ((mat==0)?Wq1:((mat==1)?Wk1:((mat==2)?Wv1:Ws1)));
    short* WtN = conv ? WtN2 : WtN1;
    #pragma unroll
    for (int t=0;t<16;t++){
      int idx = t*256+tid; int r = idx>>6, c = idx&63;
      lds[r*65+c] = f2bf(W[(size_t)(i0+r)*256 + o0 + c]);
    }
    __syncthreads();
    #pragma unroll
    for (int t=0;t<4;t++){
      int idx = t*256+tid; int r = idx>>4, c4 = (idx&15)*4;
      s16x4 o;
      o[0]=lds[(c4+0)*65+r]; o[1]=lds[(c4+1)*65+r];
      o[2]=lds[(c4+2)*65+r]; o[3]=lds[(c4+3)*65+r];
      *(s16x4*)(WtN + (mat<<16) + (o0+r)*256 + i0 + c4) = o;
    }
  } else if (b < 160){
    int b2 = b-128;                 // 32 blocks: 4 k-tiles x 8 o-tiles
    int k0 = (b2>>3)*64, o0 = (b2&7)*64;   // o0 in 0..511, k0 in 0..192
    const float* We = (o0 < 256) ? We1 : We2;
    int oc = o0 & 255;
    #pragma unroll
    for (int t=0;t<16;t++){
      int idx = t*256+tid; int r = idx>>6, c = idx&63;
      int k = k0+r;
      lds[r*65+c] = (k<ED) ? f2bf(We[(size_t)k*256 + oc + c]) : (short)0;
    }
    __syncthreads();
    #pragma unroll
    for (int t=0;t<4;t++){
      int idx = t*256+tid; int r = idx>>4, c4 = (idx&15)*4;
      if (k0 + c4 < EDP){
        s16x4 o;
        o[0]=lds[(c4+0)*65+r]; o[1]=lds[(c4+1)*65+r];
        o[2]=lds[(c4+2)*65+r]; o[3]=lds[(c4+3)*65+r];
        *(s16x4*)(WtE + (size_t)(o0+r)*EDP + k0 + c4) = o;
      }
    }
  } else {
    int conv = b - 160;
    float* biasN = conv ? biasN2 : biasN1;
    for (int t = tid; t < 1024; t += 256){
      const float* bb = conv ? ((t<256)?bq2:((t<512)?bk2:((t<768)?bv2:bs2)))
                             : ((t<256)?bq1:((t<512)?bk1:((t<768)?bv1:bs1)));
      biasN[t] = bb[t&255];
    }
  }
}

// ---------------- CSR build ----------------
#define SCAN_NBLK 196
__global__ __launch_bounds__(256) void scan_p1(const int* __restrict__ deg, int* __restrict__ part){
  int t = threadIdx.x;
  int i = blockIdx.x*256 + t;
  int v = (i<N_NODES)? deg[i] : 0;
  #pragma unroll
  for (int off=32; off; off>>=1) v += __shfl_xor(v, off, 64);
  __shared__ int s[4];
  if ((t&63)==0) s[t>>6] = v;
  __syncthreads();
  if (t==0) part[blockIdx.x] = s[0]+s[1]+s[2]+s[3];
}
__global__ __launch_bounds__(256) void scan_p2(int* __restrict__ part){
  __shared__ int s[256];
  int t = threadIdx.x;
  int v = (t<SCAN_NBLK)? part[t] : 0;
  s[t] = v; __syncthreads();
  for (int off=1; off<256; off<<=1){
    int x = (t>=off)? s[t-off] : 0;
    __syncthreads();
    s[t] += x;
    __syncthreads();
  }
  part[t] = (t==0)? 0 : s[t-1];
}
// also zeroes cursor
__global__ __launch_bounds__(256) void scan_p3(const int* __restrict__ deg,
    const int* __restrict__ part, int* __restrict__ rowptr, int* __restrict__ cursor){
  __shared__ int s[256];
  int t = threadIdx.x;
  int i = blockIdx.x*256 + t;
  int v = (i<N_NODES)? deg[i] : 0;
  s[t] = v; __syncthreads();
  for (int off=1; off<256; off<<=1){
    int x = (t>=off)? s[t-off] : 0;
    __syncthreads();
    s[t] += x;
    __syncthreads();
  }
  if (i < N_NODES){ rowptr[i+1] = part[blockIdx.x] + s[t]; cursor[i] = 0; }
  if (i == 0) rowptr[0] = 0;
}
// csr entries premultiplied to byte offsets:
//   x = src*2048 (QKVS row), y = e*1024 (Eemb row, 512 bf16 cols for both convs)
__global__ __launch_bounds__(256) void scatter_edges(
    const int* __restrict__ src, const int* __restrict__ dst,
    const int* __restrict__ rowptr, int* __restrict__ cursor, int2* __restrict__ csr)
{
  int e = blockIdx.x*256 + threadIdx.x;
  if (e < N_EDGES){
    int d = dst[e];
    int pos = atomicAdd(&cursor[d], 1);
    csr[rowptr[d] + pos] = make_int2(src[e]<<11, e<<10);
  }
}

// ---------------- tiled GEMM: out = A(bf16,[Mpad][K]) @ Bt^T (Bt=[N][K] bf16) ----
// r13/r15/r18-proven structure (the 776.3us base): 128x128 tile, 4 waves,
// BK=64, single-buffered LDS 32KB, within-row XOR chunk swizzle (conflicts
// 7M->0), same-XCD A-sharing block swizzle (r12: FETCH 245->57MB), and r18's
// WIDE EPILOGUE (C routed through dead LDS staging: 8 x global_store_dwordx4
// per thread instead of 64 x 2B stores -> edge GEMM 150->127us).
// (r14 dbuf REGRESSED: occupancy. r16 launch fusion REGRESSED: L2 dilution.
//  r11 NT stores: WRITE 2x. r10 n-fastest: cross-XCD. r4/r5: tile/staging.)
template<int K, int NLD, bool HAS_BIAS, int SWZ_NB>
__global__ __launch_bounds__(256) void gemm_bt(
    const short* __restrict__ A, const short* __restrict__ Bt,
    const float* __restrict__ bias, short* __restrict__ out, int M)
{
  __shared__ short As[128*64];   // 16 KB
  __shared__ short Bs[128*64];   // 16 KB
  int tid = threadIdx.x;
  int lane = tid & 63, wave = tid >> 6;

  int mblk, nblk;
  if (SWZ_NB > 0){
    int bid = blockIdx.x;
    int MB  = gridDim.x / SWZ_NB;
    int MB8 = MB & ~7;
    int body = MB8 * SWZ_NB;
    if (bid < body){
      int xcd = bid & 7, w = bid >> 3;
      nblk = w % SWZ_NB;
      mblk = (w / SWZ_NB) * 8 + xcd;
    } else {
      int r = bid - body;
      mblk = MB8 + r / SWZ_NB;
      nblk = r % SWZ_NB;
    }
  } else {
    mblk = blockIdx.x; nblk = blockIdx.y;
  }
  int m0 = mblk*128, n0 = nblk*128;

  // staging: wave w, lane l covers row w*8+(l>>3) (+ i*32 per instruction),
  // LDS chunk l&7; global source chunk (l&7)^((l>>3)&7)  [row&7 == (l>>3)&7]
  int srow = wave*8 + (lane>>3);
  int sx   = ((lane&7) ^ ((lane>>3)&7))*8;      // swizzled source col (shorts)
  const short* gA = A + (size_t)(m0+srow)*K + sx;
  const short* gB = Bt + (size_t)(n0+srow)*K + sx;
  short* ldsA = As + wave*512;                  // + i*2048 per instruction
  short* ldsB = Bs + wave*512;

  int wr = wave>>1, wc = wave&1;
  int fr = lane & 15;
  int kq = lane >> 4;
  int frx = fr & 7;
  const short* arb = As + (wr*64 + fr)*64;      // fragment row base (64-col rows)
  const short* brb = Bs + (wc*64 + fr)*64;

  f32x4 acc[4][4];
  #pragma unroll
  for (int a=0;a<4;a++)
    #pragma unroll
    for (int b=0;b<4;b++) acc[a][b] = (f32x4){0.f,0.f,0.f,0.f};

  for (int k0=0; k0<K; k0+=64){
    __syncthreads();
    #pragma unroll
    for (int i=0;i<4;i++){
      gload_lds16(gA + (size_t)i*32*K + k0, ldsA + i*2048);
      gload_lds16(gB + (size_t)i*32*K + k0, ldsB + i*2048);
    }
    __syncthreads();

    #pragma unroll
    for (int ks=0; ks<2; ks++){
      int cA = ((ks*4 + kq) ^ frx)*8;           // swizzled read chunk offset
      bf16x8 af[4], bf[4];
      #pragma unroll
      for (int fm=0;fm<4;fm++) af[fm] = *(const bf16x8*)(arb + fm*1024 + cA);
      #pragma unroll
      for (int fn=0;fn<4;fn++) bf[fn] = *(const bf16x8*)(brb + fn*1024 + cA);
      #pragma unroll
      for (int fm=0;fm<4;fm++)
        #pragma unroll
        for (int fn=0;fn<4;fn++)
          acc[fm][fn] = __builtin_amdgcn_mfma_f32_16x16x32_bf16(af[fm], bf[fn], acc[fm][fn], 0, 0, 0);
    }
  }

  // ---- wide epilogue via LDS round-trip (r18) ----
  __syncthreads();                // no wave still reads As/Bs fragments
  short* E = (wave < 2) ? (As + wave*4096) : (Bs + (wave-2)*4096);  // 8KB/wave
  int cr = (lane>>4)*4;
  int cc = lane & 15;
  int er  = lane>>3;              // 0..7
  int ec8 = (lane&7)*8;           // 0..56 shorts (16B chunks)
  int colbase = n0 + wc*64;
  #pragma unroll
  for (int fm=0;fm<4;fm++){
    #pragma unroll
    for (int fn=0;fn<4;fn++){
      float bv = HAS_BIAS ? bias[colbase + fn*16 + cc] : 0.f;
      #pragma unroll
      for (int i=0;i<4;i++)
        E[(cr+i)*72 + fn*16 + cc] = f2bf(acc[fm][fn][i] + bv);
    }
    #pragma unroll
    for (int rr=0; rr<2; rr++){
      int r = rr*8 + er;
      int row = m0 + wr*64 + fm*16 + r;
      s16x8 v = *(const s16x8*)(E + r*72 + ec8);
      if (row < M)
        *(s16x8*)(out + (size_t)row*NLD + colbase + ec8) = v;
    }
  }
}

// ---------------- fused edge phase ----------------
// ONE WAVE PER NODE (4 nodes per block, no __syncthreads, no LDS merge).
// 32 lanes per edge, 8 channels per lane (16B loads), TWO edges in flight
// (half = lane>>5). csr entry for the NEXT iteration software-prefetched.
// Eemb rows are 512 bf16 (both convs); caller passes base +0 (conv1) or +256.
__global__ __launch_bounds__(256) void edge_phase_kernel(
    const short* __restrict__ QKVS, const short* __restrict__ Eemb,
    const int* __restrict__ rowptr, const int2* __restrict__ csr,
    short* __restrict__ out_bf, float* __restrict__ out_f, int relu)
{
  int tid = threadIdx.x, wave = tid>>6, lane = tid&63;
  int node = blockIdx.x*4 + wave;
  if (node >= N_NODES){
    if (node < MP_NODE && out_bf){
      s16x4 z; z[0]=0; z[1]=0; z[2]=0; z[3]=0;
      *(s16x4*)(out_bf + (size_t)node*256 + lane*4) = z;
    }
    return;
  }
  int half = lane>>5;          // which edge of the pair
  int hl   = lane&31;          // channel-group 0..31 (8 ch each)
  int c8   = hl*8;
  const unsigned short* base = (const unsigned short*)QKVS + (size_t)node*1024;

  u16x8 qu = *(const u16x8*)(base + c8);
  float q[8];
  #pragma unroll
  for (int j=0;j<8;j++) q[j] = bf2f(qu[j])*0.125f;

  int beg = rowptr[node], end = rowptr[node+1];
  float l = 0.f;
  float a[8];
  #pragma unroll
  for (int j=0;j<8;j++) a[j] = 0.f;
  int kb = 512 + hl*16;        // K byte offset within QKVS row for this lane
  int ebo = hl*16;             // Eemb byte offset within row-half

  if (beg < end){
    int j0 = beg + half;
    int2 se = csr[(j0 < end) ? j0 : (end-1)];
    for (int idx = beg; idx < end; idx += 2){
      int jn = idx + 2 + half;
      int2 se_n = csr[(jn < end) ? jn : (end-1)];   // prefetch next iteration
      int j = idx + half;
      const char* Kp = (const char*)QKVS + (unsigned)(se.x + kb);
      const char* Ep = (const char*)Eemb + (unsigned)(se.y + ebo);
      u16x8 ku = *(const u16x8*)Kp;
      u16x8 vu = *(const u16x8*)(Kp + 512);   // V block
      u16x8 eu = *(const u16x8*)Ep;
      float vv[8];
      float t = 0.f;
      #pragma unroll
      for (int c=0;c<8;c++){
        float ef = bf2f(eu[c]);
        float kf = bf2f(ku[c]) + ef;
        vv[c]    = bf2f(vu[c]) + ef;
        t += q[c]*kf;
      }
      t += __shfl_xor(t, 1, 64);
      t += __shfl_xor(t, 2, 64);
      t += __shfl_xor(t, 4, 64);
      float p = (j < end) ? __expf(t) : 0.f;
      l += p;
      #pragma unroll
      for (int c=0;c<8;c++) a[c] += p*vv[c];
      se = se_n;
    }
  }

  // merge the two halves (each summed a disjoint subset of edges)
  l += __shfl_xor(l, 32, 64);
  #pragma unroll
  for (int c=0;c<8;c++) a[c] += __shfl_xor(a[c], 32, 64);

  float inv = (l > 0.f) ? 1.0f/l : 0.f;
  u16x8 su = *(const u16x8*)(base + 768 + c8);   // skip = x@Ws + bs
  float r[8];
  #pragma unroll
  for (int c=0;c<8;c++){
    float v = a[c]*inv + bf2f(su[c]);
    r[c] = relu ? fmaxf(v, 0.f) : v;
  }

  if (out_bf){
    if (!half){
      s16x8 o;
      #pragma unroll
      for (int c=0;c<8;c++) o[c] = f2bf(r[c]);
      *(s16x8*)(out_bf + (size_t)node*256 + c8) = o;
    }
  } else {
    float4 st = half ? make_float4(r[4],r[5],r[6],r[7])
                     : make_float4(r[0],r[1],r[2],r[3]);
    *(float4*)(out_f + (size_t)node*256 + c8 + half*4) = st;
  }
}

// ---------------- launch ----------------
extern "C" void kernel_launch(void* const* d_in, const int* in_sizes, int n_in,
                              void* d_out, int out_size, void* d_ws, size_t ws_size,
                              hipStream_t stream)
{
  const float* x     = (const float*)d_in[0];
  const int*   eidx  = (const int*)d_in[1];
  const float* eattr = (const float*)d_in[2];
  const float* Wq1=(const float*)d_in[3],  *bq1=(const float*)d_in[4];
  const float* Wk1=(const float*)d_in[5],  *bk1=(const float*)d_in[6];
  const float* Wv1=(const float*)d_in[7],  *bv1=(const float*)d_in[8];
  const float* We1=(const float*)d_in[9];
  const float* Ws1=(const float*)d_in[10], *bs1=(const float*)d_in[11];
  const float* Wq2=(const float*)d_in[12], *bq2=(const float*)d_in[13];
  const float* Wk2=(const float*)d_in[14], *bk2=(const float*)d_in[15];
  const float* Wv2=(const float*)d_in[16], *bv2=(const float*)d_in[17];
  const float* We2=(const float*)d_in[18];
  const float* Ws2=(const float*)d_in[19], *bs2=(const float*)d_in[20];

  char* ws = (char*)d_ws;
  size_t off = 0;
  auto alloc = [&](size_t bytes)->char*{
    char* p = ws + off; off = (off + bytes + 255) & ~(size_t)255; return p;
  };
  short* QKVS  = (short*)alloc((size_t)N_NODES*1024*2);
  short* Eemb  = (short*)alloc((size_t)MP_EDGE*512*2);   // 512 cols: conv1|conv2
  short* x_bf  = (short*)alloc((size_t)MP_NODE*DIM*2);
  short* h_bf  = (short*)alloc((size_t)MP_NODE*DIM*2);
  short* e_bf  = (short*)alloc((size_t)MP_EDGE*EDP*2);   // K padded to 256
  short* WtN1  = (short*)alloc((size_t)4*65536*2);
  short* WtN2  = (short*)alloc((size_t)4*65536*2);
  short* WtE   = (short*)alloc((size_t)512*EDP*2);
  float* biasN1= (float*)alloc((size_t)1024*4);
  float* biasN2= (float*)alloc((size_t)1024*4);
  int*   deg   = (int*)alloc((size_t)N_NODES*4);
  int*   rowptr= (int*)alloc((size_t)(N_NODES+1)*4);
  int*   cursor= (int*)alloc((size_t)N_NODES*4);
  int*   part  = (int*)alloc((size_t)256*4);
  int2*  csr   = (int2*)alloc((size_t)N_EDGES*8);

  const int* srcp = eidx;
  const int* dstp = eidx + N_EDGES;

  const int EB = (N_EDGES + 255)/256;   // 977

  convert_x_kernel<<<MP_NODE*64/256,256,0,stream>>>(x, x_bf, deg);
  convert_e_kernel<<<MP_EDGE/E_ROWS,256,0,stream>>>(eattr, e_bf, dstp, deg);

  scan_p1<<<SCAN_NBLK,256,0,stream>>>(deg, part);
  scan_p2<<<1,256,0,stream>>>(part);
  scan_p3<<<SCAN_NBLK,256,0,stream>>>(deg, part, rowptr, cursor);
  scatter_edges<<<EB,256,0,stream>>>(srcp, dstp, rowptr, cursor, csr);

  prep_weights_all<<<162,256,0,stream>>>(
      Wq1,Wk1,Wv1,Ws1,We1,bq1,bk1,bv1,bs1,
      Wq2,Wk2,Wv2,Ws2,We2,bq2,bk2,bv2,bs2,
      WtN1,WtN2,WtE,biasN1,biasN2);

  // merged edge GEMM: Eemb[:,0:256]=e@We1, [:,256:512]=e@We2 — e_bf read ONCE.
  // 1D grid + same-XCD A-sharing swizzle (r12: FETCH 245->57MB).
  gemm_bt<EDP,512,false,4><<<(MP_EDGE/128)*4,256,0,stream>>>(e_bf, WtE, nullptr, Eemb, N_EDGES);

  // ---- conv1 ---- (node GEMM: same-XCD swizzle too, 8 sharers per A-panel)
  gemm_bt<DIM,1024,true,8><<<(MP_NODE/128)*8,256,0,stream>>>(x_bf, WtN1, biasN1, QKVS, N_NODES);
  edge_phase_kernel<<<MP_NODE/4,256,0,stream>>>(QKVS,Eemb,rowptr,csr,h_bf,nullptr,1);

  // ---- conv2 ----
  gemm_bt<DIM,1024,true,8><<<(MP_NODE/128)*8,256,0,stream>>>(h_bf, WtN2, biasN2, QKVS, N_NODES);
  edge_phase_kernel<<<N_NODES/4,256,0,stream>>>(QKVS,Eemb+256,rowptr,csr,nullptr,(float*)d_out,0);
}

// Round 20
// 755.974 us; speedup vs baseline: 1.1097x; 1.0142x over previous
//
#include <hip/hip_runtime.h>

#define N_NODES 50000
#define N_EDGES 250000
#define DIM 256          // IN = OUT = H*C
#define ED 194           // edge feature dim
#define EDP 256          // edge K padded to BK=64 multiple
#define MP_NODE 50048    // 391*128
#define MP_EDGE 250112   // 1954*128

typedef __bf16 bf16x8 __attribute__((ext_vector_type(8)));
typedef float f32x4 __attribute__((ext_vector_type(4)));
typedef short s16x8 __attribute__((ext_vector_type(8)));
typedef short s16x4 __attribute__((ext_vector_type(4)));
typedef unsigned short u16x8 __attribute__((ext_vector_type(8)));

__device__ __forceinline__ float bf2f(unsigned short b){
  union { unsigned int u; float f; } v; v.u = ((unsigned int)b)<<16; return v.f;
}
__device__ __forceinline__ short f2bf(float f){
  union { float f; unsigned int u; } v; v.f = f;
  unsigned int u = v.u;
  return (short)((u + 0x7fffu + ((u>>16)&1u))>>16);
}

// async global->LDS, 16B per lane. LDS dest = wave-uniform base + lane*16.
__device__ __forceinline__ void gload_lds16(const void* g, void* l){
  __builtin_amdgcn_global_load_lds(
      (const __attribute__((address_space(1))) unsigned int*)g,
      (__attribute__((address_space(3))) unsigned int*)l, 16, 0, 0);
}

// ---------------- input converts (fp32 -> bf16, padded) ----------------
// Also zeroes deg[] (count_deg runs later in-stream inside convert_e).
__global__ __launch_bounds__(256) void convert_x_kernel(
    const float* __restrict__ x, short* __restrict__ xb, int* __restrict__ deg)
{
  int idx = blockIdx.x*256 + threadIdx.x;       // MP_NODE*64 float4s total
  if (idx < N_NODES) deg[idx] = 0;
  s16x4 o;
  if (idx < N_NODES*64){
    float4 a = *(const float4*)(x + (size_t)idx*4);
    o[0]=f2bf(a.x); o[1]=f2bf(a.y); o[2]=f2bf(a.z); o[3]=f2bf(a.w);
  } else {
    o[0]=0; o[1]=0; o[2]=0; o[3]=0;
  }
  *(s16x4*)(xb + (size_t)idx*4) = o;
}

// Edge rows are 194 floats (776B) -> stage 32 rows through LDS with dense
// flat float4 loads, then convert+pad (to EDP=256) with coalesced stores.
// Also does count_deg for its 32 edges (r19: saves a launch; deg zeroed by
// convert_x which completes first on the in-order stream).
#define E_ROWS 32
__global__ __launch_bounds__(256) void convert_e_kernel(
    const float* __restrict__ ea, short* __restrict__ eb,
    const int* __restrict__ dst, int* __restrict__ deg)
{
  __shared__ float lds[E_ROWS*ED];              // 6208 floats = 24832 B
  int row0 = blockIdx.x * E_ROWS;
  int tid = threadIdx.x;
  if (tid < E_ROWS){
    int e = row0 + tid;
    if (e < N_EDGES) atomicAdd(&deg[dst[e]], 1);
  }
  int base = row0 * ED;                         // float index of block start
  int valid = N_EDGES*ED - base;                // may be <=0 for pad blocks

  for (int i = tid; i < E_ROWS*ED/4; i += 256){
    float4 v;
    if (i*4 < valid) v = *(const float4*)(ea + base + i*4);
    else             v = make_float4(0.f,0.f,0.f,0.f);
    *(float4*)(lds + i*4) = v;
  }
  __syncthreads();

  for (int u = tid; u < E_ROWS*32; u += 256){
    int row = u >> 5;
    int c8  = u & 31;
    int col = c8*8;
    s16x8 o;
    if (col + 8 <= ED){
      #pragma unroll
      for (int j2=0;j2<4;j2++){
        float2 f = *(const float2*)(lds + row*ED + col + j2*2);
        o[j2*2]   = f2bf(f.x);
        o[j2*2+1] = f2bf(f.y);
      }
    } else {
      #pragma unroll
      for (int j=0;j<8;j++){
        int c = col + j;
        o[j] = (c < ED) ? f2bf(lds[row*ED + c]) : (short)0;
      }
    }
    *(s16x8*)(eb + (size_t)(row0+row)*EDP + col) = o;
  }
}

// ---------------- fused weight prep: BOTH convs, one launch (162 blocks) ----
__global__ __launch_bounds__(256) void prep_weights_all(
    const float* __restrict__ Wq1, const float* __restrict__ Wk1,
    const float* __restrict__ Wv1, const float* __restrict__ Ws1,
    const float* __restrict__ We1,
    const float* __restrict__ bq1, const float* __restrict__ bk1,
    const float* __restrict__ bv1, const float* __restrict__ bs1,
    const float* __restrict__ Wq2, const float* __restrict__ Wk2,
    const float* __restrict__ Wv2, const float* __restrict__ Ws2,
    const float* __restrict__ We2,
    const float* __restrict__ bq2, const float* __restrict__ bk2,
    const float* __restrict__ bv2, const float* __restrict__ bs2,
    short* __restrict__ WtN1, short* __restrict__ WtN2,
    short* __restrict__ WtE, float* __restrict__ biasN1, float* __restrict__ biasN2)
{
  __shared__ short lds[64*65];
  int b = blockIdx.x, tid = threadIdx.x;
  if (b < 128){
    int conv = b>>6, bb = b&63;
    int mat = bb>>4, tile = bb&15;
    int i0 = (tile>>2)*64, o0 = (tile&3)*64;
    const float* W = conv ? ((mat==0)?Wq2:((mat==1)?Wk2:((mat==2)?Wv2:Ws2)))
                          : ((mat==0)?Wq1:((mat==1)?Wk1:((mat==2)?Wv1:Ws1)));
    short* WtN = conv ? WtN2 : WtN1;
    #pragma unroll
    for (int t=0;t<16;t++){
      int idx = t*256+tid; int r = idx>>6, c = idx&63;
      lds[r*65+c] = f2bf(W[(size_t)(i0+r)*256 + o0 + c]);
    }
    __syncthreads();
    #pragma unroll
    for (int t=0;t<4;t++){
      int idx = t*256+tid; int r = idx>>4, c4 = (idx&15)*4;
      s16x4 o;
      o[0]=lds[(c4+0)*65+r]; o[1]=lds[(c4+1)*65+r];
      o[2]=lds[(c4+2)*65+r]; o[3]=lds[(c4+3)*65+r];
      *(s16x4*)(WtN + (mat<<16) + (o0+r)*256 + i0 + c4) = o;
    }
  } else if (b < 160){
    int b2 = b-128;                 // 32 blocks: 4 k-tiles x 8 o-tiles
    int k0 = (b2>>3)*64, o0 = (b2&7)*64;   // o0 in 0..511, k0 in 0..192
    const float* We = (o0 < 256) ? We1 : We2;
    int oc = o0 & 255;
    #pragma unroll
    for (int t=0;t<16;t++){
      int idx = t*256+tid; int r = idx>>6, c = idx&63;
      int k = k0+r;
      lds[r*65+c] = (k<ED) ? f2bf(We[(size_t)k*256 + oc + c]) : (short)0;
    }
    __syncthreads();
    #pragma unroll
    for (int t=0;t<4;t++){
      int idx = t*256+tid; int r = idx>>4, c4 = (idx&15)*4;
      if (k0 + c4 < EDP){
        s16x4 o;
        o[0]=lds[(c4+0)*65+r]; o[1]=lds[(c4+1)*65+r];
        o[2]=lds[(c4+2)*65+r]; o[3]=lds[(c4+3)*65+r];
        *(s16x4*)(WtE + (size_t)(o0+r)*EDP + k0 + c4) = o;
      }
    }
  } else {
    int conv = b - 160;
    float* biasN = conv ? biasN2 : biasN1;
    for (int t = tid; t < 1024; t += 256){
      const float* bb = conv ? ((t<256)?bq2:((t<512)?bk2:((t<768)?bv2:bs2)))
                             : ((t<256)?bq1:((t<512)?bk1:((t<768)?bv1:bs1)));
      biasN[t] = bb[t&255];
    }
  }
}

// ---------------- CSR build ----------------
#define SCAN_NBLK 196
__global__ __launch_bounds__(256) void scan_p1(const int* __restrict__ deg, int* __restrict__ part){
  int t = threadIdx.x;
  int i = blockIdx.x*256 + t;
  int v = (i<N_NODES)? deg[i] : 0;
  #pragma unroll
  for (int off=32; off; off>>=1) v += __shfl_xor(v, off, 64);
  __shared__ int s[4];
  if ((t&63)==0) s[t>>6] = v;
  __syncthreads();
  if (t==0) part[blockIdx.x] = s[0]+s[1]+s[2]+s[3];
}
__global__ __launch_bounds__(256) void scan_p2(int* __restrict__ part){
  __shared__ int s[256];
  int t = threadIdx.x;
  int v = (t<SCAN_NBLK)? part[t] : 0;
  s[t] = v; __syncthreads();
  for (int off=1; off<256; off<<=1){
    int x = (t>=off)? s[t-off] : 0;
    __syncthreads();
    s[t] += x;
    __syncthreads();
  }
  part[t] = (t==0)? 0 : s[t-1];
}
// also zeroes cursor
__global__ __launch_bounds__(256) void scan_p3(const int* __restrict__ deg,
    const int* __restrict__ part, int* __restrict__ rowptr, int* __restrict__ cursor){
  __shared__ int s[256];
  int t = threadIdx.x;
  int i = blockIdx.x*256 + t;
  int v = (i<N_NODES)? deg[i] : 0;
  s[t] = v; __syncthreads();
  for (int off=1; off<256; off<<=1){
    int x = (t>=off)? s[t-off] : 0;
    __syncthreads();
    s[t] += x;
    __syncthreads();
  }
  if (i < N_NODES){ rowptr[i+1] = part[blockIdx.x] + s[t]; cursor[i] = 0; }
  if (i == 0) rowptr[0] = 0;
}
// csr entries premultiplied to byte offsets:
//   x = src*2048 (QKVS row), y = e*1024 (Eemb row, 512 bf16 cols for both convs)
__global__ __launch_bounds__(256) void scatter_edges(
    const int* __restrict__ src, const int* __restrict__ dst,
    const int* __restrict__ rowptr, int* __restrict__ cursor, int2* __restrict__ csr)
{
  int e = blockIdx.x*256 + threadIdx.x;
  if (e < N_EDGES){
    int d = dst[e];
    int pos = atomicAdd(&cursor[d], 1);
    csr[rowptr[d] + pos] = make_int2(src[e]<<11, e<<10);
  }
}

// ---------------- tiled GEMM: out = A(bf16,[Mpad][K]) @ Bt^T (Bt=[N][K] bf16) ----
// r13/r15/r18-proven structure (the 766.7us base): 128x128 tile, 4 waves,
// BK=64, single-buffered LDS 32KB, within-row XOR chunk swizzle (conflicts
// 7M->0), same-XCD A-sharing block swizzle (r12: FETCH 245->57MB), and r18's
// WIDE EPILOGUE (C routed through dead LDS staging: 8 x global_store_dwordx4
// per thread instead of 64 x 2B stores -> edge GEMM 150->127us).
// (r14 dbuf REGRESSED: occupancy. r16 launch fusion REGRESSED: L2 dilution.
//  r11 NT stores: WRITE 2x. r10 n-fastest: cross-XCD. r4/r5: tile/staging.)
template<int K, int NLD, bool HAS_BIAS, int SWZ_NB>
__global__ __launch_bounds__(256) void gemm_bt(
    const short* __restrict__ A, const short* __restrict__ Bt,
    const float* __restrict__ bias, short* __restrict__ out, int M)
{
  __shared__ short As[128*64];   // 16 KB
  __shared__ short Bs[128*64];   // 16 KB
  int tid = threadIdx.x;
  int lane = tid & 63, wave = tid >> 6;

  int mblk, nblk;
  if (SWZ_NB > 0){
    int bid = blockIdx.x;
    int MB  = gridDim.x / SWZ_NB;
    int MB8 = MB & ~7;
    int body = MB8 * SWZ_NB;
    if (bid < body){
      int xcd = bid & 7, w = bid >> 3;
      nblk = w % SWZ_NB;
      mblk = (w / SWZ_NB) * 8 + xcd;
    } else {
      int r = bid - body;
      mblk = MB8 + r / SWZ_NB;
      nblk = r % SWZ_NB;
    }
  } else {
    mblk = blockIdx.x; nblk = blockIdx.y;
  }
  int m0 = mblk*128, n0 = nblk*128;

  // staging: wave w, lane l covers row w*8+(l>>3) (+ i*32 per instruction),
  // LDS chunk l&7; global source chunk (l&7)^((l>>3)&7)  [row&7 == (l>>3)&7]
  int srow = wave*8 + (lane>>3);
  int sx   = ((lane&7) ^ ((lane>>3)&7))*8;      // swizzled source col (shorts)
  const short* gA = A + (size_t)(m0+srow)*K + sx;
  const short* gB = Bt + (size_t)(n0+srow)*K + sx;
  short* ldsA = As + wave*512;                  // + i*2048 per instruction
  short* ldsB = Bs + wave*512;

  int wr = wave>>1, wc = wave&1;
  int fr = lane & 15;
  int kq = lane >> 4;
  int frx = fr & 7;
  const short* arb = As + (wr*64 + fr)*64;      // fragment row base (64-col rows)
  const short* brb = Bs + (wc*64 + fr)*64;

  f32x4 acc[4][4];
  #pragma unroll
  for (int a=0;a<4;a++)
    #pragma unroll
    for (int b=0;b<4;b++) acc[a][b] = (f32x4){0.f,0.f,0.f,0.f};

  for (int k0=0; k0<K; k0+=64){
    __syncthreads();
    #pragma unroll
    for (int i=0;i<4;i++){
      gload_lds16(gA + (size_t)i*32*K + k0, ldsA + i*2048);
      gload_lds16(gB + (size_t)i*32*K + k0, ldsB + i*2048);
    }
    __syncthreads();

    #pragma unroll
    for (int ks=0; ks<2; ks++){
      int cA = ((ks*4 + kq) ^ frx)*8;           // swizzled read chunk offset
      bf16x8 af[4], bf[4];
      #pragma unroll
      for (int fm=0;fm<4;fm++) af[fm] = *(const bf16x8*)(arb + fm*1024 + cA);
      #pragma unroll
      for (int fn=0;fn<4;fn++) bf[fn] = *(const bf16x8*)(brb + fn*1024 + cA);
      #pragma unroll
      for (int fm=0;fm<4;fm++)
        #pragma unroll
        for (int fn=0;fn<4;fn++)
          acc[fm][fn] = __builtin_amdgcn_mfma_f32_16x16x32_bf16(af[fm], bf[fn], acc[fm][fn], 0, 0, 0);
    }
  }

  // ---- wide epilogue via LDS round-trip (r18) ----
  __syncthreads();                // no wave still reads As/Bs fragments
  short* E = (wave < 2) ? (As + wave*4096) : (Bs + (wave-2)*4096);  // 8KB/wave
  int cr = (lane>>4)*4;
  int cc = lane & 15;
  int er  = lane>>3;              // 0..7
  int ec8 = (lane&7)*8;           // 0..56 shorts (16B chunks)
  int colbase = n0 + wc*64;
  #pragma unroll
  for (int fm=0;fm<4;fm++){
    #pragma unroll
    for (int fn=0;fn<4;fn++){
      float bv = HAS_BIAS ? bias[colbase + fn*16 + cc] : 0.f;
      #pragma unroll
      for (int i=0;i<4;i++)
        E[(cr+i)*72 + fn*16 + cc] = f2bf(acc[fm][fn][i] + bv);
    }
    #pragma unroll
    for (int rr=0; rr<2; rr++){
      int r = rr*8 + er;
      int row = m0 + wr*64 + fm*16 + r;
      s16x8 v = *(const s16x8*)(E + r*72 + ec8);
      if (row < M)
        *(s16x8*)(out + (size_t)row*NLD + colbase + ec8) = v;
    }
  }
}

// ---------------- fused edge phase ----------------
// ONE WAVE PER NODE (4 nodes per block, no __syncthreads, no LDS merge).
// 32 lanes per edge, 8 channels per lane (16B loads), TWO edges in flight
// (half = lane>>5). csr entry for the NEXT iteration software-prefetched.
// Eemb rows are 512 bf16 (both convs); caller passes base +0 (conv1) or +256.
// r20: Eemb gather is NON-TEMPORAL — each Eemb row is read exactly once per
// call (128MB single-use stream), so caching it evicts the ~5x-reused QKVS
// K/V working set from L2/L3. NT load = pure allocation hint, identical
// semantics, no write-amplification risk (unlike r11's NT stores).
__global__ __launch_bounds__(256) void edge_phase_kernel(
    const short* __restrict__ QKVS, const short* __restrict__ Eemb,
    const int* __restrict__ rowptr, const int2* __restrict__ csr,
    short* __restrict__ out_bf, float* __restrict__ out_f, int relu)
{
  int tid = threadIdx.x, wave = tid>>6, lane = tid&63;
  int node = blockIdx.x*4 + wave;
  if (node >= N_NODES){
    if (node < MP_NODE && out_bf){
      s16x4 z; z[0]=0; z[1]=0; z[2]=0; z[3]=0;
      *(s16x4*)(out_bf + (size_t)node*256 + lane*4) = z;
    }
    return;
  }
  int half = lane>>5;          // which edge of the pair
  int hl   = lane&31;          // channel-group 0..31 (8 ch each)
  int c8   = hl*8;
  const unsigned short* base = (const unsigned short*)QKVS + (size_t)node*1024;

  u16x8 qu = *(const u16x8*)(base + c8);
  float q[8];
  #pragma unroll
  for (int j=0;j<8;j++) q[j] = bf2f(qu[j])*0.125f;

  int beg = rowptr[node], end = rowptr[node+1];
  float l = 0.f;
  float a[8];
  #pragma unroll
  for (int j=0;j<8;j++) a[j] = 0.f;
  int kb = 512 + hl*16;        // K byte offset within QKVS row for this lane
  int ebo = hl*16;             // Eemb byte offset within row-half

  if (beg < end){
    int j0 = beg + half;
    int2 se = csr[(j0 < end) ? j0 : (end-1)];
    for (int idx = beg; idx < end; idx += 2){
      int jn = idx + 2 + half;
      int2 se_n = csr[(jn < end) ? jn : (end-1)];   // prefetch next iteration
      int j = idx + half;
      const char* Kp = (const char*)QKVS + (unsigned)(se.x + kb);
      const char* Ep = (const char*)Eemb + (unsigned)(se.y + ebo);
      u16x8 ku = *(const u16x8*)Kp;
      u16x8 vu = *(const u16x8*)(Kp + 512);   // V block
      u16x8 eu = __builtin_nontemporal_load((const u16x8*)Ep);
      float vv[8];
      float t = 0.f;
      #pragma unroll
      for (int c=0;c<8;c++){
        float ef = bf2f(eu[c]);
        float kf = bf2f(ku[c]) + ef;
        vv[c]    = bf2f(vu[c]) + ef;
        t += q[c]*kf;
      }
      t += __shfl_xor(t, 1, 64);
      t += __shfl_xor(t, 2, 64);
      t += __shfl_xor(t, 4, 64);
      float p = (j < end) ? __expf(t) : 0.f;
      l += p;
      #pragma unroll
      for (int c=0;c<8;c++) a[c] += p*vv[c];
      se = se_n;
    }
  }

  // merge the two halves (each summed a disjoint subset of edges)
  l += __shfl_xor(l, 32, 64);
  #pragma unroll
  for (int c=0;c<8;c++) a[c] += __shfl_xor(a[c], 32, 64);

  float inv = (l > 0.f) ? 1.0f/l : 0.f;
  u16x8 su = *(const u16x8*)(base + 768 + c8);   // skip = x@Ws + bs
  float r[8];
  #pragma unroll
  for (int c=0;c<8;c++){
    float v = a[c]*inv + bf2f(su[c]);
    r[c] = relu ? fmaxf(v, 0.f) : v;
  }

  if (out_bf){
    if (!half){
      s16x8 o;
      #pragma unroll
      for (int c=0;c<8;c++) o[c] = f2bf(r[c]);
      *(s16x8*)(out_bf + (size_t)node*256 + c8) = o;
    }
  } else {
    float4 st = half ? make_float4(r[4],r[5],r[6],r[7])
                     : make_float4(r[0],r[1],r[2],r[3]);
    *(float4*)(out_f + (size_t)node*256 + c8 + half*4) = st;
  }
}

// ---------------- launch ----------------
extern "C" void kernel_launch(void* const* d_in, const int* in_sizes, int n_in,
                              void* d_out, int out_size, void* d_ws, size_t ws_size,
                              hipStream_t stream)
{
  const float* x     = (const float*)d_in[0];
  const int*   eidx  = (const int*)d_in[1];
  const float* eattr = (const float*)d_in[2];
  const float* Wq1=(const float*)d_in[3],  *bq1=(const float*)d_in[4];
  const float* Wk1=(const float*)d_in[5],  *bk1=(const float*)d_in[6];
  const float* Wv1=(const float*)d_in[7],  *bv1=(const float*)d_in[8];
  const float* We1=(const float*)d_in[9];
  const float* Ws1=(const float*)d_in[10], *bs1=(const float*)d_in[11];
  const float* Wq2=(const float*)d_in[12], *bq2=(const float*)d_in[13];
  const float* Wk2=(const float*)d_in[14], *bk2=(const float*)d_in[15];
  const float* Wv2=(const float*)d_in[16], *bv2=(const float*)d_in[17];
  const float* We2=(const float*)d_in[18];
  const float* Ws2=(const float*)d_in[19], *bs2=(const float*)d_in[20];

  char* ws = (char*)d_ws;
  size_t off = 0;
  auto alloc = [&](size_t bytes)->char*{
    char* p = ws + off; off = (off + bytes + 255) & ~(size_t)255; return p;
  };
  short* QKVS  = (short*)alloc((size_t)N_NODES*1024*2);
  short* Eemb  = (short*)alloc((size_t)MP_EDGE*512*2);   // 512 cols: conv1|conv2
  short* x_bf  = (short*)alloc((size_t)MP_NODE*DIM*2);
  short* h_bf  = (short*)alloc((size_t)MP_NODE*DIM*2);
  short* e_bf  = (short*)alloc((size_t)MP_EDGE*EDP*2);   // K padded to 256
  short* WtN1  = (short*)alloc((size_t)4*65536*2);
  short* WtN2  = (short*)alloc((size_t)4*65536*2);
  short* WtE   = (short*)alloc((size_t)512*EDP*2);
  float* biasN1= (float*)alloc((size_t)1024*4);
  float* biasN2= (float*)alloc((size_t)1024*4);
  int*   deg   = (int*)alloc((size_t)N_NODES*4);
  int*   rowptr= (int*)alloc((size_t)(N_NODES+1)*4);
  int*   cursor= (int*)alloc((size_t)N_NODES*4);
  int*   part  = (int*)alloc((size_t)256*4);
  int2*  csr   = (int2*)alloc((size_t)N_EDGES*8);

  const int* srcp = eidx;
  const int* dstp = eidx + N_EDGES;

  const int EB = (N_EDGES + 255)/256;   // 977

  convert_x_kernel<<<MP_NODE*64/256,256,0,stream>>>(x, x_bf, deg);
  convert_e_kernel<<<MP_EDGE/E_ROWS,256,0,stream>>>(eattr, e_bf, dstp, deg);

  scan_p1<<<SCAN_NBLK,256,0,stream>>>(deg, part);
  scan_p2<<<1,256,0,stream>>>(part);
  scan_p3<<<SCAN_NBLK,256,0,stream>>>(deg, part, rowptr, cursor);
  scatter_edges<<<EB,256,0,stream>>>(srcp, dstp, rowptr, cursor, csr);

  prep_weights_all<<<162,256,0,stream>>>(
      Wq1,Wk1,Wv1,Ws1,We1,bq1,bk1,bv1,bs1,
      Wq2,Wk2,Wv2,Ws2,We2,bq2,bk2,bv2,bs2,
      WtN1,WtN2,WtE,biasN1,biasN2);

  // merged edge GEMM: Eemb[:,0:256]=e@We1, [:,256:512]=e@We2 — e_bf read ONCE.
  // 1D grid + same-XCD A-sharing swizzle (r12: FETCH 245->57MB).
  gemm_bt<EDP,512,false,4><<<(MP_EDGE/128)*4,256,0,stream>>>(e_bf, WtE, nullptr, Eemb, N_EDGES);

  // ---- conv1 ---- (node GEMM: same-XCD swizzle too, 8 sharers per A-panel)
  gemm_bt<DIM,1024,true,8><<<(MP_NODE/128)*8,256,0,stream>>>(x_bf, WtN1, biasN1, QKVS, N_NODES);
  edge_phase_kernel<<<MP_NODE/4,256,0,stream>>>(QKVS,Eemb,rowptr,csr,h_bf,nullptr,1);

  // ---- conv2 ----
  gemm_bt<DIM,1024,true,8><<<(MP_NODE/128)*8,256,0,stream>>>(h_bf, WtN2, biasN2, QKVS, N_NODES);
  edge_phase_kernel<<<N_NODES/4,256,0,stream>>>(QKVS,Eemb+256,rowptr,csr,nullptr,(float*)d_out,0);
}